// Round 1
// baseline (786.982 us; speedup 1.0000x reference)
//
#include <hip/hip_runtime.h>
#include <math.h>

#define BB 4
#define CC 64
#define OC 64
#define HH 128
#define WW 128
#define KKN 9
#define CK (CC*KKN)   // 576

// ---------------- Kernel A: fused offset(18ch) + mask(9ch, sigmoid) 3x3 conv ----------------
__global__ __launch_bounds__(256) void offmask_conv(
    const float* __restrict__ x,
    const float* __restrict__ w_off, const float* __restrict__ b_off,
    const float* __restrict__ w_mask, const float* __restrict__ b_mask,
    float* __restrict__ off_out, float* __restrict__ mask_out)
{
    int idx = blockIdx.x * 256 + threadIdx.x;
    int w  = idx % WW;
    int h  = (idx / WW) % HH;
    int oc = (idx / (WW * HH)) % 27;
    int b  = idx / (27 * WW * HH);
    if (b >= BB) return;

    const float* wp; float bias;
    if (oc < 18) { wp = w_off  + oc * CC * 9;        bias = b_off[oc]; }
    else         { wp = w_mask + (oc - 18) * CC * 9; bias = b_mask[oc - 18]; }

    float acc = bias;
    const float* xb = x + b * CC * HH * WW;
    int yb = h - 1, xb0 = w - 1;
    for (int c = 0; c < CC; ++c) {
        const float* xc = xb + c * HH * WW;
        const float* wc = wp + c * 9;
        #pragma unroll
        for (int i = 0; i < 3; ++i) {
            int y = yb + i;
            if ((unsigned)y >= (unsigned)HH) continue;
            const float* xr = xc + y * WW;
            #pragma unroll
            for (int j = 0; j < 3; ++j) {
                int xx = xb0 + j;
                if ((unsigned)xx >= (unsigned)WW) continue;
                acc = fmaf(xr[xx], wc[i * 3 + j], acc);
            }
        }
    }

    if (oc < 18) {
        off_out[((b * 18 + oc) * HH + h) * WW + w] = acc;
    } else {
        float s = 1.0f / (1.0f + expf(-acc));
        mask_out[((b * 9 + (oc - 18)) * HH + h) * WW + w] = s;
    }
}

// ---------------- Kernel B: transpose w_dcn [64][576] -> wT [576][64] ----------------
__global__ __launch_bounds__(256) void transpose_w(
    const float* __restrict__ w_dcn, float* __restrict__ wT)
{
    int i = blockIdx.x * 256 + threadIdx.x;  // over OC*CK
    if (i >= OC * CK) return;
    int oc = i / CK, p = i % CK;
    wT[p * OC + oc] = w_dcn[i];
}

// ---------------- Kernel C: deformable conv ----------------
// One 256-thread block handles 4 consecutive pixels (same image row, W%4==0).
__global__ __launch_bounds__(256) void deform(
    const float* __restrict__ x,
    const float* __restrict__ off, const float* __restrict__ mask,
    const float* __restrict__ wT, const float* __restrict__ b_dcn,
    float* __restrict__ out)
{
    const int PIX = 4;
    __shared__ float acc[PIX][CK];        // 9216 B
    __shared__ float swt[PIX][KKN][4];    // tap weights (mask folded in)
    __shared__ int   sidx[PIX][KKN][4];   // clamped flat indices into an HxW plane
    __shared__ float outs[OC][PIX + 1];   // padded to dodge bank conflicts

    int tid = threadIdx.x;
    int pixbase = blockIdx.x * PIX;          // over B*H*W
    int wo0 = pixbase % WW;                  // 4 pixels: wo0..wo0+3, same row
    int ho  = (pixbase / WW) % HH;
    int b   = pixbase / (WW * HH);

    // Phase 0: bilinear tap setup, 36 threads = (pixel, k)
    if (tid < PIX * KKN) {
        int pp = tid / KKN;
        int k  = tid % KKN;
        int wo = wo0 + pp;
        float dy = off[((b * 18 + 2 * k    ) * HH + ho) * WW + wo];
        float dx = off[((b * 18 + 2 * k + 1) * HH + ho) * WW + wo];
        float m  = mask[((b * 9 + k) * HH + ho) * WW + wo];
        float py = dy + (float)(k / 3) + (float)(ho - 1);
        float px = dx + (float)(k % 3) + (float)(wo - 1);
        float y0f = floorf(py), x0f = floorf(px);
        float ly = py - y0f, lx = px - x0f;
        int y0 = (int)y0f, x0 = (int)x0f;
        #pragma unroll
        for (int t = 0; t < 4; ++t) {
            int yi = y0 + (t >> 1);
            int xi = x0 + (t & 1);
            float wy = (t >> 1) ? ly : 1.0f - ly;
            float wx = (t & 1)  ? lx : 1.0f - lx;
            bool valid = ((unsigned)yi < (unsigned)HH) && ((unsigned)xi < (unsigned)WW);
            int yc = min(max(yi, 0), HH - 1);
            int xc = min(max(xi, 0), WW - 1);
            sidx[pp][k][t] = yc * WW + xc;
            swt[pp][k][t]  = valid ? wy * wx * m : 0.0f;
        }
    }
    __syncthreads();

    // Phase 1: fill acc[pix][c*9+k], 2304 entries / 256 threads = 9 each
    for (int e = tid; e < PIX * CK; e += 256) {
        int pp  = e / CK;
        int rem = e % CK;
        int c = rem / KKN, k = rem % KKN;
        const float* xc = x + (b * CC + c) * HH * WW;
        float v = xc[sidx[pp][k][0]] * swt[pp][k][0]
                + xc[sidx[pp][k][1]] * swt[pp][k][1]
                + xc[sidx[pp][k][2]] * swt[pp][k][2]
                + xc[sidx[pp][k][3]] * swt[pp][k][3];
        acc[pp][rem] = v;
    }
    __syncthreads();

    // Phase 2: wave wv = pixel wv, lane = oc. K=576 dot product.
    int wv = tid >> 6;
    int oc = tid & 63;
    float s = b_dcn[oc];
    const float4* av = (const float4*)acc[wv];
    #pragma unroll 4
    for (int p4 = 0; p4 < CK / 4; ++p4) {
        float4 a = av[p4];
        int p = p4 * 4;
        s = fmaf(a.x, wT[(p + 0) * OC + oc], s);
        s = fmaf(a.y, wT[(p + 1) * OC + oc], s);
        s = fmaf(a.z, wT[(p + 2) * OC + oc], s);
        s = fmaf(a.w, wT[(p + 3) * OC + oc], s);
    }
    outs[oc][wv] = s;
    __syncthreads();

    // coalesced-ish output: thread t writes (oc2 = t/4, pp2 = t%4)
    int oc2 = tid >> 2, pp2 = tid & 3;
    out[((b * OC + oc2) * HH + ho) * WW + wo0 + pp2] = outs[oc2][pp2];
}

extern "C" void kernel_launch(void* const* d_in, const int* in_sizes, int n_in,
                              void* d_out, int out_size, void* d_ws, size_t ws_size,
                              hipStream_t stream) {
    const float* x      = (const float*)d_in[0];
    const float* w_off  = (const float*)d_in[1];
    const float* b_off  = (const float*)d_in[2];
    const float* w_mask = (const float*)d_in[3];
    const float* b_mask = (const float*)d_in[4];
    const float* w_dcn  = (const float*)d_in[5];
    const float* b_dcn  = (const float*)d_in[6];

    float* out     = (float*)d_out;                       // B*OC*H*W
    float* off_out = out + BB * OC * HH * WW;             // B*18*H*W (output 1)
    float* mask_ws = (float*)d_ws;                        // B*9*H*W
    float* wT      = mask_ws + BB * 9 * HH * WW;          // 576*64

    // Kernel B: weight transpose (independent)
    transpose_w<<<(OC * CK + 255) / 256, 256, 0, stream>>>(w_dcn, wT);

    // Kernel A: offset + mask conv
    int total_a = BB * 27 * HH * WW;
    offmask_conv<<<(total_a + 255) / 256, 256, 0, stream>>>(
        x, w_off, b_off, w_mask, b_mask, off_out, mask_ws);

    // Kernel C: deformable conv
    int nblocks = (BB * HH * WW) / 4;
    deform<<<nblocks, 256, 0, stream>>>(x, off_out, mask_ws, wT, b_dcn, out);
}

// Round 2
// 203.932 us; speedup vs baseline: 3.8590x; 3.8590x over previous
//
#include <hip/hip_runtime.h>
#include <math.h>

#define BB 4
#define CC 64
#define OCN 64
#define HH 128
#define WW 128
#define HW (HH*WW)
#define KKN 9
#define CK 576          // C*KK
#define CHUNK 8         // channels per LDS chunk in deform
#define PROWS (CHUNK*KKN)  // 72

// ---------------- prep: wT[576][64], wre[c][g][i][j] (27 oc regrouped), rebias[27] ----------
__global__ __launch_bounds__(256) void prep(
    const float* __restrict__ w_dcn, const float* __restrict__ w_off,
    const float* __restrict__ b_off, const float* __restrict__ w_mask,
    const float* __restrict__ b_mask,
    float* __restrict__ wT, float* __restrict__ wre, float* __restrict__ rebias)
{
    int i = blockIdx.x * 256 + threadIdx.x;
    if (i < OCN * CK) {                        // transpose w_dcn [64][576] -> [576][64]
        int oc = i / CK, p = i % CK;
        wT[p * OCN + oc] = w_dcn[i];
    }
    int j = i - OCN * CK;
    if (j >= 0 && j < CC * 27 * 9) {           // wre[((c*3+g)*9+ii)*9+jj], oc = g*9+ii
        int jj = j % 9;
        int ii = (j / 9) % 9;
        int g  = (j / 81) % 3;
        int c  = j / 243;
        int oc = g * 9 + ii;
        float v;
        if (oc < 18) v = w_off[(oc * CC + c) * 9 + jj];
        else         v = w_mask[((oc - 18) * CC + c) * 9 + jj];
        wre[j] = v;
    }
    int r = i - OCN * CK - CC * 27 * 9;
    if (r >= 0 && r < 27) {
        rebias[r] = (r < 18) ? b_off[r] : b_mask[r - 18];
    }
}

// ---------------- offmask: 9 oc per thread, weights via uniform s_loads ----------------
// grid = 256 pixel-blocks * 3 oc-groups; block covers 256 consecutive pixels (2 rows)
__global__ __launch_bounds__(256) void offmask(
    const float* __restrict__ x, const float* __restrict__ wre,
    const float* __restrict__ rebias,
    float* __restrict__ off_out, float* __restrict__ mask_out)
{
    int g   = blockIdx.x / 256;                    // 0..2 (uniform)
    int pix = (blockIdx.x % 256) * 256 + threadIdx.x;
    int w = pix % WW;
    int h = (pix / WW) % HH;
    int b = pix / HW;

    float acc[9];
    #pragma unroll
    for (int i = 0; i < 9; ++i) acc[i] = rebias[g * 9 + i];

    const float* xb = x + b * CC * HW;

    #pragma unroll 2
    for (int c = 0; c < CC; ++c) {
        const float* xc = xb + c * HW;
        float xv[9];
        #pragma unroll
        for (int j = 0; j < 9; ++j) {
            int dy = j / 3 - 1, dx = j % 3 - 1;
            int yy = h + dy, xx = w + dx;
            bool valid = ((unsigned)yy < (unsigned)HH) && ((unsigned)xx < (unsigned)WW);
            int yc = min(max(yy, 0), HH - 1);
            int xc2 = min(max(xx, 0), WW - 1);
            float v = xc[yc * WW + xc2];           // always in-bounds (clamped)
            xv[j] = valid ? v : 0.0f;
        }
        const float* wc = wre + (c * 3 + g) * 81;  // uniform -> s_load
        #pragma unroll
        for (int i = 0; i < 9; ++i) {
            #pragma unroll
            for (int j = 0; j < 9; ++j)
                acc[i] = fmaf(xv[j], wc[i * 9 + j], acc[i]);
        }
    }

    if (g < 2) {
        #pragma unroll
        for (int i = 0; i < 9; ++i)
            off_out[((b * 18 + g * 9 + i) * HH + h) * WW + w] = acc[i];
    } else {
        #pragma unroll
        for (int i = 0; i < 9; ++i) {
            float s = 1.0f / (1.0f + expf(-acc[i]));
            mask_out[((b * 9 + i) * HH + h) * WW + w] = s;
        }
    }
}

// ---------------- deform: lane = pixel, wave = 16-oc slice, LDS im2col chunks ----------
// block = 256 threads, 64 consecutive pixels of one row. grid = B*H*2 = 1024 blocks.
__global__ __launch_bounds__(256) void deform(
    const float* __restrict__ x,
    const float* __restrict__ off, const float* __restrict__ mask,
    const float* __restrict__ wT, const float* __restrict__ b_dcn,
    float* __restrict__ out)
{
    __shared__ float accs[PROWS][64];     // 18.4 KB
    __shared__ float swt[4][KKN][64];     // 9.2 KB
    __shared__ int   sidx[4][KKN][64];    // 9.2 KB

    int tid  = threadIdx.x;
    int lane = tid & 63;
    int wv   = __builtin_amdgcn_readfirstlane(tid >> 6);
    int oc0  = wv * 16;

    int wo0 = (blockIdx.x & 1) * 64;
    int row = (blockIdx.x >> 1) & (HH - 1);
    int b   = blockIdx.x >> 8;

    // phase 0: bilinear tap setup for the 64 pixels x 9 kernel positions
    for (int e = tid; e < KKN * 64; e += 256) {
        int k = e >> 6, pix = e & 63;
        int wo = wo0 + pix;
        float dy = off[((b * 18 + 2 * k    ) * HH + row) * WW + wo];
        float dx = off[((b * 18 + 2 * k + 1) * HH + row) * WW + wo];
        float m  = mask[((b * 9 + k) * HH + row) * WW + wo];
        float py = dy + (float)(k / 3) + (float)(row - 1);
        float px = dx + (float)(k % 3) + (float)(wo - 1);
        float y0f = floorf(py), x0f = floorf(px);
        float ly = py - y0f, lx = px - x0f;
        int y0 = (int)y0f, x0 = (int)x0f;
        #pragma unroll
        for (int t = 0; t < 4; ++t) {
            int yi = y0 + (t >> 1), xi = x0 + (t & 1);
            float wy = (t >> 1) ? ly : 1.0f - ly;
            float wx = (t & 1)  ? lx : 1.0f - lx;
            bool valid = ((unsigned)yi < (unsigned)HH) && ((unsigned)xi < (unsigned)WW);
            int yc = min(max(yi, 0), HH - 1);
            int xc = min(max(xi, 0), WW - 1);
            sidx[t][k][pix] = yc * WW + xc;
            swt[t][k][pix]  = valid ? wy * wx * m : 0.0f;
        }
    }

    float accv[16];
    #pragma unroll
    for (int j = 0; j < 16; ++j) accv[j] = b_dcn[oc0 + j];   // uniform s_load

    for (int cc = 0; cc < CC / CHUNK; ++cc) {
        __syncthreads();   // taps ready / previous compute done
        // fill: im2col chunk (8 channels x 9 taps x 64 pixels), near-coalesced gathers
        const float* xbase = x + (b * CC + cc * CHUNK) * HW;
        for (int e = tid; e < PROWS * 64; e += 256) {
            int pix = e & 63;
            int pr  = e >> 6;            // c*9+k
            int k   = pr % KKN;
            int c   = pr / KKN;
            const float* xc = xbase + c * HW;
            float v = xc[sidx[0][k][pix]] * swt[0][k][pix]
                    + xc[sidx[1][k][pix]] * swt[1][k][pix]
                    + xc[sidx[2][k][pix]] * swt[2][k][pix]
                    + xc[sidx[3][k][pix]] * swt[3][k][pix];
            accs[pr][pix] = v;
        }
        __syncthreads();
        // compute: per K-step 1 conflict-free ds_read + 16 fma with SGPR weights
        const float* wrow = wT + (size_t)(cc * PROWS) * OCN + oc0;   // uniform
        #pragma unroll 4
        for (int p = 0; p < PROWS; ++p) {
            float a = accs[p][lane];
            #pragma unroll
            for (int j = 0; j < 16; ++j)
                accv[j] = fmaf(a, wrow[p * OCN + j], accv[j]);
        }
    }

    #pragma unroll
    for (int j = 0; j < 16; ++j)
        out[((b * OCN + oc0 + j) * HH + row) * WW + wo0 + lane] = accv[j];
}

extern "C" void kernel_launch(void* const* d_in, const int* in_sizes, int n_in,
                              void* d_out, int out_size, void* d_ws, size_t ws_size,
                              hipStream_t stream) {
    const float* x      = (const float*)d_in[0];
    const float* w_off  = (const float*)d_in[1];
    const float* b_off  = (const float*)d_in[2];
    const float* w_mask = (const float*)d_in[3];
    const float* b_mask = (const float*)d_in[4];
    const float* w_dcn  = (const float*)d_in[5];
    const float* b_dcn  = (const float*)d_in[6];

    float* out     = (float*)d_out;                       // B*OC*H*W
    float* off_out = out + BB * OCN * HW;                 // B*18*H*W (output 1)
    float* mask_ws = (float*)d_ws;                        // B*9*H*W
    float* wT      = mask_ws + BB * 9 * HW;               // 576*64
    float* wre     = wT + CK * OCN;                       // 64*27*9
    float* rebias  = wre + CC * 27 * 9;                   // 27

    int prep_total = OCN * CK + CC * 27 * 9 + 27;
    prep<<<(prep_total + 255) / 256, 256, 0, stream>>>(
        w_dcn, w_off, b_off, w_mask, b_mask, wT, wre, rebias);

    offmask<<<256 * 3, 256, 0, stream>>>(x, wre, rebias, off_out, mask_ws);

    deform<<<BB * HH * 2, 256, 0, stream>>>(x, off_out, mask_ws, wT, b_dcn, out);
}

// Round 3
// 125.071 us; speedup vs baseline: 6.2923x; 1.6305x over previous
//
#include <hip/hip_runtime.h>
#include <hip/hip_bf16.h>
#include <math.h>

#define BB 4
#define CC 64
#define OCN 64
#define HH 128
#define WW 128
#define HW (HH*WW)
#define KKN 9
#define CK 576            // C*KK, GEMM K
#define KC 192            // K per chunk (3 taps * 64 ch)
#define APAD 200          // LDS row stride (bf16) for accs

typedef short short8 __attribute__((ext_vector_type(8)));
typedef float floatx4 __attribute__((ext_vector_type(4)));

__device__ __forceinline__ float bf2f(__hip_bfloat16 h) {
    unsigned short u = *reinterpret_cast<unsigned short*>(&h);
    return __uint_as_float(((unsigned)u) << 16);
}
__device__ __forceinline__ short f2bfs(float f) {
    __hip_bfloat16 h = __float2bfloat16(f);
    return *reinterpret_cast<short*>(&h);
}

// ---------------- prep: wTf (MFMA B-fragment pack, bf16), wre, rebias ----------------
// wTf flat index ((s*4+nt)*64+l)*8+j : lane l, reg j of B-frag for K-step s, oc-tile nt.
// K-order: kk = ktap*64 + c  (tap-major, matches gather LDS layout).
__global__ __launch_bounds__(256) void prep(
    const float* __restrict__ w_dcn, const float* __restrict__ w_off,
    const float* __restrict__ b_off, const float* __restrict__ w_mask,
    const float* __restrict__ b_mask,
    __hip_bfloat16* __restrict__ wTf, float* __restrict__ wre, float* __restrict__ rebias)
{
    int i = blockIdx.x * 256 + threadIdx.x;
    if (i < 18 * 4 * 64 * 8) {
        int jj = i & 7;
        int l  = (i >> 3) & 63;
        int nt = (i >> 9) & 3;
        int s  = i >> 11;
        int oc = nt * 16 + (l & 15);
        int kk = s * 32 + ((l >> 4) << 3) + jj;
        int c  = kk & 63;
        int kt = kk >> 6;
        wTf[i] = __float2bfloat16(w_dcn[(oc * CC + c) * 9 + kt]);
    }
    int j = i - 18 * 4 * 64 * 8;
    if (j >= 0 && j < CC * 27 * 9) {           // wre[((c*3+g)*9+ii)*9+jj], oc = g*9+ii
        int jj = j % 9;
        int ii = (j / 9) % 9;
        int g  = (j / 81) % 3;
        int c  = j / 243;
        int oc = g * 9 + ii;
        float v;
        if (oc < 18) v = w_off[(oc * CC + c) * 9 + jj];
        else         v = w_mask[((oc - 18) * CC + c) * 9 + jj];
        wre[j] = v;
    }
    int r = j - CC * 27 * 9;
    if (r >= 0 && r < 27) rebias[r] = (r < 18) ? b_off[r] : b_mask[r - 18];
}

// ---------------- transpose_x: x[b][c][h][w] f32 -> xt[b][h*w][c] bf16 ----------------
__global__ __launch_bounds__(256) void transpose_x(
    const float* __restrict__ x, __hip_bfloat16* __restrict__ xt)
{
    __shared__ float tile[64][65];
    int tid = threadIdx.x;
    int tpix = blockIdx.x & 255;
    int b    = blockIdx.x >> 8;
    int pixbase = tpix * 64;
    const float* xb = x + (size_t)b * CC * HW;
    int lanep = tid & 63;
    #pragma unroll
    for (int i = 0; i < 16; ++i) {
        int c = (tid >> 6) * 16 + i;
        tile[c][lanep] = xb[(size_t)c * HW + pixbase + lanep];
    }
    __syncthreads();
    __hip_bfloat16* xo = xt + ((size_t)b * HW + pixbase) * CC;
    #pragma unroll
    for (int i = 0; i < 8; ++i) {
        int idx = tid + i * 256;
        int pixl = idx >> 5, c2 = idx & 31;
        unsigned short lo = (unsigned short)(unsigned)f2bfs(tile[2 * c2][pixl]);
        unsigned short hi = (unsigned short)(unsigned)f2bfs(tile[2 * c2 + 1][pixl]);
        unsigned packed = lo | ((unsigned)hi << 16);
        *reinterpret_cast<unsigned*>(&xo[(size_t)pixl * CC + c2 * 2]) = packed;
    }
}

// ---------------- offmask: unchanged from round 2 (fp32 exact) ----------------
__global__ __launch_bounds__(256) void offmask(
    const float* __restrict__ x, const float* __restrict__ wre,
    const float* __restrict__ rebias,
    float* __restrict__ off_out, float* __restrict__ mask_out)
{
    int g   = blockIdx.x / 256;
    int pix = (blockIdx.x % 256) * 256 + threadIdx.x;
    int w = pix % WW;
    int h = (pix / WW) % HH;
    int b = pix / HW;

    float acc[9];
    #pragma unroll
    for (int i = 0; i < 9; ++i) acc[i] = rebias[g * 9 + i];

    const float* xb = x + (size_t)b * CC * HW;

    #pragma unroll 2
    for (int c = 0; c < CC; ++c) {
        const float* xc = xb + (size_t)c * HW;
        float xv[9];
        #pragma unroll
        for (int j = 0; j < 9; ++j) {
            int dy = j / 3 - 1, dx = j % 3 - 1;
            int yy = h + dy, xx = w + dx;
            bool valid = ((unsigned)yy < (unsigned)HH) && ((unsigned)xx < (unsigned)WW);
            int yc = min(max(yy, 0), HH - 1);
            int xc2 = min(max(xx, 0), WW - 1);
            float v = xc[yc * WW + xc2];
            xv[j] = valid ? v : 0.0f;
        }
        const float* wc = wre + (c * 3 + g) * 81;
        #pragma unroll
        for (int i = 0; i < 9; ++i) {
            #pragma unroll
            for (int j = 0; j < 9; ++j)
                acc[i] = fmaf(xv[j], wc[i * 9 + j], acc[i]);
        }
    }

    if (g < 2) {
        #pragma unroll
        for (int i = 0; i < 9; ++i)
            off_out[((b * 18 + g * 9 + i) * HH + h) * WW + w] = acc[i];
    } else {
        #pragma unroll
        for (int i = 0; i < 9; ++i) {
            float s = 1.0f / (1.0f + expf(-acc[i]));
            mask_out[((b * 9 + i) * HH + h) * WW + w] = s;
        }
    }
}

// ---------------- deform: bilinear gather (channel-last bf16) + MFMA GEMM ----------------
// block = 256 threads / 4 waves, 64 pixels (half row). Wave wv: pixels wv*16..+15, all 64 oc.
__global__ __launch_bounds__(256) void deform(
    const __hip_bfloat16* __restrict__ xt,
    const float* __restrict__ off, const float* __restrict__ mask,
    const __hip_bfloat16* __restrict__ wTf, const float* __restrict__ b_dcn,
    float* __restrict__ out)
{
    __shared__ __align__(16) __hip_bfloat16 accs[64][APAD];   // 25600 B
    __shared__ unsigned short sidx[4][KKN][64];               // 4608 B
    __shared__ __hip_bfloat16 swt[4][KKN][64];                // 4608 B

    int tid  = threadIdx.x;
    int lane = tid & 63;
    int wv   = __builtin_amdgcn_readfirstlane(tid >> 6);

    int wo0 = (blockIdx.x & 1) * 64;
    int row = (blockIdx.x >> 1) & (HH - 1);
    int b   = blockIdx.x >> 8;

    // phase 0: bilinear tap setup (9 k x 64 pixels)
    for (int e = tid; e < KKN * 64; e += 256) {
        int k = e >> 6, pix = e & 63;
        int wo = wo0 + pix;
        float dy = off[((b * 18 + 2 * k    ) * HH + row) * WW + wo];
        float dx = off[((b * 18 + 2 * k + 1) * HH + row) * WW + wo];
        float m  = mask[((b * 9 + k) * HH + row) * WW + wo];
        float py = dy + (float)(k / 3) + (float)(row - 1);
        float px = dx + (float)(k % 3) + (float)(wo - 1);
        float y0f = floorf(py), x0f = floorf(px);
        float ly = py - y0f, lx = px - x0f;
        int y0 = (int)y0f, x0 = (int)x0f;
        #pragma unroll
        for (int t = 0; t < 4; ++t) {
            int yi = y0 + (t >> 1), xi = x0 + (t & 1);
            float wy = (t >> 1) ? ly : 1.0f - ly;
            float wx = (t & 1)  ? lx : 1.0f - lx;
            bool valid = ((unsigned)yi < (unsigned)HH) && ((unsigned)xi < (unsigned)WW);
            int yc = min(max(yi, 0), HH - 1);
            int xc = min(max(xi, 0), WW - 1);
            sidx[t][k][pix] = (unsigned short)(yc * WW + xc);
            swt[t][k][pix]  = __float2bfloat16(valid ? wy * wx * m : 0.0f);
        }
    }
    __syncthreads();

    floatx4 accv[4] = {{0,0,0,0},{0,0,0,0},{0,0,0,0},{0,0,0,0}};
    const __hip_bfloat16* xtb = xt + (size_t)b * HW * CC;

    for (int chunk = 0; chunk < 3; ++chunk) {
        // gather: 1536 items = 3 taps x 8 c8-groups x 64 pixels
        #pragma unroll
        for (int it = 0; it < 6; ++it) {
            int e = tid + it * 256;
            int pix  = e & 63;
            int rest = e >> 6;        // 0..23
            int kl   = rest >> 3;     // 0..2
            int c8   = rest & 7;
            int k    = chunk * 3 + kl;
            float a0 = 0.f, a1 = 0.f, a2 = 0.f, a3 = 0.f, a4 = 0.f, a5 = 0.f, a6 = 0.f, a7 = 0.f;
            #pragma unroll
            for (int t = 0; t < 4; ++t) {
                float wt = bf2f(swt[t][k][pix]);
                int idx = (int)sidx[t][k][pix];
                short8 v = *reinterpret_cast<const short8*>(xtb + (size_t)idx * CC + c8 * 8);
                a0 = fmaf(wt, __uint_as_float(((unsigned)(unsigned short)v[0]) << 16), a0);
                a1 = fmaf(wt, __uint_as_float(((unsigned)(unsigned short)v[1]) << 16), a1);
                a2 = fmaf(wt, __uint_as_float(((unsigned)(unsigned short)v[2]) << 16), a2);
                a3 = fmaf(wt, __uint_as_float(((unsigned)(unsigned short)v[3]) << 16), a3);
                a4 = fmaf(wt, __uint_as_float(((unsigned)(unsigned short)v[4]) << 16), a4);
                a5 = fmaf(wt, __uint_as_float(((unsigned)(unsigned short)v[5]) << 16), a5);
                a6 = fmaf(wt, __uint_as_float(((unsigned)(unsigned short)v[6]) << 16), a6);
                a7 = fmaf(wt, __uint_as_float(((unsigned)(unsigned short)v[7]) << 16), a7);
            }
            short8 o;
            o[0] = f2bfs(a0); o[1] = f2bfs(a1); o[2] = f2bfs(a2); o[3] = f2bfs(a3);
            o[4] = f2bfs(a4); o[5] = f2bfs(a5); o[6] = f2bfs(a6); o[7] = f2bfs(a7);
            *reinterpret_cast<short8*>(&accs[pix][kl * 64 + c8 * 8]) = o;
        }
        __syncthreads();

        // MFMA: 6 K-steps of 32, 4 oc-tiles
        int arow = wv * 16 + (lane & 15);
        int kreg = (lane >> 4) << 3;
        #pragma unroll
        for (int step = 0; step < 6; ++step) {
            int s = chunk * 6 + step;
            short8 a = *reinterpret_cast<const short8*>(&accs[arow][step * 32 + kreg]);
            const short8* bp = reinterpret_cast<const short8*>(wTf) + (size_t)(s * 4) * 64 + lane;
            accv[0] = __builtin_amdgcn_mfma_f32_16x16x32_bf16(a, bp[0],   accv[0], 0, 0, 0);
            accv[1] = __builtin_amdgcn_mfma_f32_16x16x32_bf16(a, bp[64],  accv[1], 0, 0, 0);
            accv[2] = __builtin_amdgcn_mfma_f32_16x16x32_bf16(a, bp[128], accv[2], 0, 0, 0);
            accv[3] = __builtin_amdgcn_mfma_f32_16x16x32_bf16(a, bp[192], accv[3], 0, 0, 0);
        }
        if (chunk < 2) __syncthreads();
    }

    // epilogue: D layout col=lane&15 (oc), row=(lane>>4)*4+reg (pixel); 4 consecutive pixels -> float4
    int pcol = wo0 + wv * 16 + ((lane >> 4) << 2);
    #pragma unroll
    for (int nt = 0; nt < 4; ++nt) {
        int oc = nt * 16 + (lane & 15);
        float bias = b_dcn[oc];
        floatx4 o = accv[nt];
        o[0] += bias; o[1] += bias; o[2] += bias; o[3] += bias;
        *reinterpret_cast<floatx4*>(&out[(((size_t)b * OCN + oc) * HH + row) * WW + pcol]) = o;
    }
}

extern "C" void kernel_launch(void* const* d_in, const int* in_sizes, int n_in,
                              void* d_out, int out_size, void* d_ws, size_t ws_size,
                              hipStream_t stream) {
    const float* x      = (const float*)d_in[0];
    const float* w_off  = (const float*)d_in[1];
    const float* b_off  = (const float*)d_in[2];
    const float* w_mask = (const float*)d_in[3];
    const float* b_mask = (const float*)d_in[4];
    const float* w_dcn  = (const float*)d_in[5];
    const float* b_dcn  = (const float*)d_in[6];

    float* out     = (float*)d_out;                       // B*OC*H*W
    float* off_out = out + (size_t)BB * OCN * HW;         // B*18*H*W (output 1)

    float* mask_ws = (float*)d_ws;                        // B*9*H*W f32
    float* wre     = mask_ws + (size_t)BB * 9 * HW;       // 64*27*9 f32
    float* rebias  = wre + CC * 27 * 9;                   // 32 f32 (padded)
    __hip_bfloat16* xt  = (__hip_bfloat16*)(rebias + 32); // B*HW*C bf16
    __hip_bfloat16* wTf = xt + (size_t)BB * HW * CC;      // 18*4*64*8 bf16

    int prep_total = 18 * 4 * 64 * 8 + CC * 27 * 9 + 27;
    prep<<<(prep_total + 255) / 256, 256, 0, stream>>>(
        w_dcn, w_off, b_off, w_mask, b_mask, wTf, wre, rebias);

    transpose_x<<<BB * 256, 256, 0, stream>>>(x, xt);

    offmask<<<256 * 3, 256, 0, stream>>>(x, wre, rebias, off_out, mask_ws);

    deform<<<BB * HH * 2, 256, 0, stream>>>(xt, off_out, mask_ws, wTf, b_dcn, out);
}

// Round 4
// 83.372 us; speedup vs baseline: 9.4394x; 1.5002x over previous
//
#include <hip/hip_runtime.h>
#include <hip/hip_bf16.h>
#include <math.h>

#define BB 4
#define CC 64
#define OCN 64
#define HH 128
#define WW 128
#define HW (HH*WW)
#define KKN 9
#define CK 576            // C*KK, GEMM K
#define APAD 200          // LDS row stride (bf16) for accs tiles

typedef short short8 __attribute__((ext_vector_type(8)));
typedef float floatx4 __attribute__((ext_vector_type(4)));

__device__ __forceinline__ float bf2f(__hip_bfloat16 h) {
    unsigned short u = *reinterpret_cast<unsigned short*>(&h);
    return __uint_as_float(((unsigned)u) << 16);
}
__device__ __forceinline__ short f2bfs(float f) {
    __hip_bfloat16 h = __float2bfloat16(f);
    return *reinterpret_cast<short*>(&h);
}

// ---------------- prep: wTf (dcn B-frags), wOf (off/mask B-frags, 27->32 oc), rebias ----
// B-frag pack: frag[((s*NT+nt)*64+l)*8+j] = W[oc = nt*16+(l&15)][kk = s*32+((l>>4)<<3)+j]
// K-order: kk = ktap*64 + c (tap-major, matches gather LDS layout).
__global__ __launch_bounds__(256) void prep(
    const float* __restrict__ w_dcn, const float* __restrict__ w_off,
    const float* __restrict__ b_off, const float* __restrict__ w_mask,
    const float* __restrict__ b_mask,
    __hip_bfloat16* __restrict__ wTf, __hip_bfloat16* __restrict__ wOf,
    float* __restrict__ rebias)
{
    int i = blockIdx.x * 256 + threadIdx.x;
    if (i < 18 * 4 * 64 * 8) {                 // wTf: 18 K-steps x 4 oc-tiles
        int jj = i & 7;
        int l  = (i >> 3) & 63;
        int nt = (i >> 9) & 3;
        int s  = i >> 11;
        int oc = nt * 16 + (l & 15);
        int kk = s * 32 + ((l >> 4) << 3) + jj;
        int c  = kk & 63;
        int kt = kk >> 6;
        wTf[i] = __float2bfloat16(w_dcn[(oc * CC + c) * 9 + kt]);
    }
    int j = i - 18 * 4 * 64 * 8;
    if (j >= 0 && j < 18 * 2 * 64 * 8) {       // wOf: 18 K-steps x 2 oc-tiles (27 used)
        int jj = j & 7;
        int l  = (j >> 3) & 63;
        int nt = (j >> 9) & 1;
        int s  = j >> 10;
        int oc = nt * 16 + (l & 15);
        int kk = s * 32 + ((l >> 4) << 3) + jj;
        int c  = kk & 63;
        int kt = kk >> 6;
        float v = 0.0f;
        if (oc < 18)      v = w_off[(oc * CC + c) * 9 + kt];
        else if (oc < 27) v = w_mask[((oc - 18) * CC + c) * 9 + kt];
        wOf[j] = __float2bfloat16(v);
    }
    int r = j - 18 * 2 * 64 * 8;
    if (r >= 0 && r < 27) rebias[r] = (r < 18) ? b_off[r] : b_mask[r - 18];
}

// ---------------- transpose_x: x[b][c][h][w] f32 -> xt[b][h*w][c] bf16 ----------------
__global__ __launch_bounds__(256) void transpose_x(
    const float* __restrict__ x, __hip_bfloat16* __restrict__ xt)
{
    __shared__ float tile[64][65];
    int tid = threadIdx.x;
    int tpix = blockIdx.x & 255;
    int b    = blockIdx.x >> 8;
    int pixbase = tpix * 64;
    const float* xb = x + (size_t)b * CC * HW;
    int lanep = tid & 63;
    #pragma unroll
    for (int i = 0; i < 16; ++i) {
        int c = (tid >> 6) * 16 + i;
        tile[c][lanep] = xb[(size_t)c * HW + pixbase + lanep];
    }
    __syncthreads();
    __hip_bfloat16* xo = xt + ((size_t)b * HW + pixbase) * CC;
    #pragma unroll
    for (int i = 0; i < 8; ++i) {
        int idx = tid + i * 256;
        int pixl = idx >> 5, c2 = idx & 31;
        unsigned short lo = (unsigned short)(unsigned)f2bfs(tile[2 * c2][pixl]);
        unsigned short hi = (unsigned short)(unsigned)f2bfs(tile[2 * c2 + 1][pixl]);
        unsigned packed = lo | ((unsigned)hi << 16);
        *reinterpret_cast<unsigned*>(&xo[(size_t)pixl * CC + c2 * 2]) = packed;
    }
}

// ---------------- offmask: 3x3 conv as MFMA GEMM [64pix x 576] x [576 x 32] ------------
// block = 256 threads / 4 waves, 64 pixels (half row). grid = B*H*2.
__global__ __launch_bounds__(256) void offmask(
    const __hip_bfloat16* __restrict__ xt,
    const __hip_bfloat16* __restrict__ wOf, const float* __restrict__ rebias,
    float* __restrict__ off_out, float* __restrict__ mask_out)
{
    __shared__ __align__(16) __hip_bfloat16 accs[64][APAD];   // 25600 B

    int tid  = threadIdx.x;
    int lane = tid & 63;
    int wv   = __builtin_amdgcn_readfirstlane(tid >> 6);

    int wo0 = (blockIdx.x & 1) * 64;
    int row = (blockIdx.x >> 1) & (HH - 1);
    int b   = blockIdx.x >> 8;

    floatx4 accv[2] = {{0,0,0,0},{0,0,0,0}};
    const __hip_bfloat16* xtb = xt + (size_t)b * HW * CC;
    const short8 zero8 = {0,0,0,0,0,0,0,0};

    for (int chunk = 0; chunk < 3; ++chunk) {   // chunk = ky row of the 3x3
        int y = row + chunk - 1;
        bool yvalid = (unsigned)y < (unsigned)HH;
        #pragma unroll
        for (int it = 0; it < 6; ++it) {
            int e = tid + it * 256;
            int pix  = e & 63;
            int rest = e >> 6;        // 0..23
            int kl   = rest >> 3;     // kx 0..2
            int c8   = rest & 7;
            int xw   = wo0 + pix + kl - 1;
            bool valid = yvalid && ((unsigned)xw < (unsigned)WW);
            short8 v = zero8;
            if (valid)
                v = *reinterpret_cast<const short8*>(xtb + ((size_t)y * WW + xw) * CC + c8 * 8);
            *reinterpret_cast<short8*>(&accs[pix][kl * 64 + c8 * 8]) = v;
        }
        __syncthreads();

        int arow = wv * 16 + (lane & 15);
        int kreg = (lane >> 4) << 3;
        #pragma unroll
        for (int step = 0; step < 6; ++step) {
            int s = chunk * 6 + step;
            short8 a = *reinterpret_cast<const short8*>(&accs[arow][step * 32 + kreg]);
            const short8* bp = reinterpret_cast<const short8*>(wOf) + (size_t)(s * 2) * 64 + lane;
            accv[0] = __builtin_amdgcn_mfma_f32_16x16x32_bf16(a, bp[0],  accv[0], 0, 0, 0);
            accv[1] = __builtin_amdgcn_mfma_f32_16x16x32_bf16(a, bp[64], accv[1], 0, 0, 0);
        }
        if (chunk < 2) __syncthreads();
    }

    // D layout: col = lane&15 (oc), row = (lane>>4)*4+reg (pixel) -> float4 stores
    int pcol = wo0 + wv * 16 + ((lane >> 4) << 2);
    #pragma unroll
    for (int nt = 0; nt < 2; ++nt) {
        int oc = nt * 16 + (lane & 15);
        if (oc < 18) {
            float bias = rebias[oc];
            floatx4 o = accv[nt];
            o[0] += bias; o[1] += bias; o[2] += bias; o[3] += bias;
            *reinterpret_cast<floatx4*>(&off_out[(((size_t)b * 18 + oc) * HH + row) * WW + pcol]) = o;
        } else if (oc < 27) {
            float bias = rebias[oc];
            floatx4 o = accv[nt];
            #pragma unroll
            for (int q = 0; q < 4; ++q) o[q] = 1.0f / (1.0f + expf(-(o[q] + bias)));
            *reinterpret_cast<floatx4*>(&mask_out[(((size_t)b * 9 + (oc - 18)) * HH + row) * WW + pcol]) = o;
        }
    }
}

// ---------------- deform: bilinear gather (channel-last bf16) + MFMA GEMM ----------------
// block = 256 threads / 4 waves, 64 pixels (half row). Wave wv: pixels wv*16..+15, all 64 oc.
__global__ __launch_bounds__(256) void deform(
    const __hip_bfloat16* __restrict__ xt,
    const float* __restrict__ off, const float* __restrict__ mask,
    const __hip_bfloat16* __restrict__ wTf, const float* __restrict__ b_dcn,
    float* __restrict__ out)
{
    __shared__ __align__(16) __hip_bfloat16 accs[64][APAD];   // 25600 B
    __shared__ unsigned short sidx[4][KKN][64];               // 4608 B
    __shared__ __hip_bfloat16 swt[4][KKN][64];                // 4608 B

    int tid  = threadIdx.x;
    int lane = tid & 63;
    int wv   = __builtin_amdgcn_readfirstlane(tid >> 6);

    int wo0 = (blockIdx.x & 1) * 64;
    int row = (blockIdx.x >> 1) & (HH - 1);
    int b   = blockIdx.x >> 8;

    // phase 0: bilinear tap setup (9 k x 64 pixels)
    for (int e = tid; e < KKN * 64; e += 256) {
        int k = e >> 6, pix = e & 63;
        int wo = wo0 + pix;
        float dy = off[((b * 18 + 2 * k    ) * HH + row) * WW + wo];
        float dx = off[((b * 18 + 2 * k + 1) * HH + row) * WW + wo];
        float m  = mask[((b * 9 + k) * HH + row) * WW + wo];
        float py = dy + (float)(k / 3) + (float)(row - 1);
        float px = dx + (float)(k % 3) + (float)(wo - 1);
        float y0f = floorf(py), x0f = floorf(px);
        float ly = py - y0f, lx = px - x0f;
        int y0 = (int)y0f, x0 = (int)x0f;
        #pragma unroll
        for (int t = 0; t < 4; ++t) {
            int yi = y0 + (t >> 1), xi = x0 + (t & 1);
            float wy = (t >> 1) ? ly : 1.0f - ly;
            float wx = (t & 1)  ? lx : 1.0f - lx;
            bool valid = ((unsigned)yi < (unsigned)HH) && ((unsigned)xi < (unsigned)WW);
            int yc = min(max(yi, 0), HH - 1);
            int xc = min(max(xi, 0), WW - 1);
            sidx[t][k][pix] = (unsigned short)(yc * WW + xc);
            swt[t][k][pix]  = __float2bfloat16(valid ? wy * wx * m : 0.0f);
        }
    }
    __syncthreads();

    floatx4 accv[4] = {{0,0,0,0},{0,0,0,0},{0,0,0,0},{0,0,0,0}};
    const __hip_bfloat16* xtb = xt + (size_t)b * HW * CC;

    for (int chunk = 0; chunk < 3; ++chunk) {
        // gather: 1536 items = 3 taps x 8 c8-groups x 64 pixels
        #pragma unroll
        for (int it = 0; it < 6; ++it) {
            int e = tid + it * 256;
            int pix  = e & 63;
            int rest = e >> 6;        // 0..23
            int kl   = rest >> 3;     // 0..2
            int c8   = rest & 7;
            int k    = chunk * 3 + kl;
            float a0 = 0.f, a1 = 0.f, a2 = 0.f, a3 = 0.f, a4 = 0.f, a5 = 0.f, a6 = 0.f, a7 = 0.f;
            #pragma unroll
            for (int t = 0; t < 4; ++t) {
                float wt = bf2f(swt[t][k][pix]);
                int idx = (int)sidx[t][k][pix];
                short8 v = *reinterpret_cast<const short8*>(xtb + (size_t)idx * CC + c8 * 8);
                a0 = fmaf(wt, __uint_as_float(((unsigned)(unsigned short)v[0]) << 16), a0);
                a1 = fmaf(wt, __uint_as_float(((unsigned)(unsigned short)v[1]) << 16), a1);
                a2 = fmaf(wt, __uint_as_float(((unsigned)(unsigned short)v[2]) << 16), a2);
                a3 = fmaf(wt, __uint_as_float(((unsigned)(unsigned short)v[3]) << 16), a3);
                a4 = fmaf(wt, __uint_as_float(((unsigned)(unsigned short)v[4]) << 16), a4);
                a5 = fmaf(wt, __uint_as_float(((unsigned)(unsigned short)v[5]) << 16), a5);
                a6 = fmaf(wt, __uint_as_float(((unsigned)(unsigned short)v[6]) << 16), a6);
                a7 = fmaf(wt, __uint_as_float(((unsigned)(unsigned short)v[7]) << 16), a7);
            }
            short8 o;
            o[0] = f2bfs(a0); o[1] = f2bfs(a1); o[2] = f2bfs(a2); o[3] = f2bfs(a3);
            o[4] = f2bfs(a4); o[5] = f2bfs(a5); o[6] = f2bfs(a6); o[7] = f2bfs(a7);
            *reinterpret_cast<short8*>(&accs[pix][kl * 64 + c8 * 8]) = o;
        }
        __syncthreads();

        // MFMA: 6 K-steps of 32, 4 oc-tiles
        int arow = wv * 16 + (lane & 15);
        int kreg = (lane >> 4) << 3;
        #pragma unroll
        for (int step = 0; step < 6; ++step) {
            int s = chunk * 6 + step;
            short8 a = *reinterpret_cast<const short8*>(&accs[arow][step * 32 + kreg]);
            const short8* bp = reinterpret_cast<const short8*>(wTf) + (size_t)(s * 4) * 64 + lane;
            accv[0] = __builtin_amdgcn_mfma_f32_16x16x32_bf16(a, bp[0],   accv[0], 0, 0, 0);
            accv[1] = __builtin_amdgcn_mfma_f32_16x16x32_bf16(a, bp[64],  accv[1], 0, 0, 0);
            accv[2] = __builtin_amdgcn_mfma_f32_16x16x32_bf16(a, bp[128], accv[2], 0, 0, 0);
            accv[3] = __builtin_amdgcn_mfma_f32_16x16x32_bf16(a, bp[192], accv[3], 0, 0, 0);
        }
        if (chunk < 2) __syncthreads();
    }

    // epilogue: D layout col=lane&15 (oc), row=(lane>>4)*4+reg (pixel); float4 stores
    int pcol = wo0 + wv * 16 + ((lane >> 4) << 2);
    #pragma unroll
    for (int nt = 0; nt < 4; ++nt) {
        int oc = nt * 16 + (lane & 15);
        float bias = b_dcn[oc];
        floatx4 o = accv[nt];
        o[0] += bias; o[1] += bias; o[2] += bias; o[3] += bias;
        *reinterpret_cast<floatx4*>(&out[(((size_t)b * OCN + oc) * HH + row) * WW + pcol]) = o;
    }
}

extern "C" void kernel_launch(void* const* d_in, const int* in_sizes, int n_in,
                              void* d_out, int out_size, void* d_ws, size_t ws_size,
                              hipStream_t stream) {
    const float* x      = (const float*)d_in[0];
    const float* w_off  = (const float*)d_in[1];
    const float* b_off  = (const float*)d_in[2];
    const float* w_mask = (const float*)d_in[3];
    const float* b_mask = (const float*)d_in[4];
    const float* w_dcn  = (const float*)d_in[5];
    const float* b_dcn  = (const float*)d_in[6];

    float* out     = (float*)d_out;                       // B*OC*H*W
    float* off_out = out + (size_t)BB * OCN * HW;         // B*18*H*W (output 1)

    float* mask_ws = (float*)d_ws;                        // B*9*H*W f32
    float* rebias  = mask_ws + (size_t)BB * 9 * HW;       // 32 f32 (padded)
    __hip_bfloat16* xt  = (__hip_bfloat16*)(rebias + 32); // B*HW*C bf16
    __hip_bfloat16* wTf = xt + (size_t)BB * HW * CC;      // 18*4*64*8 bf16
    __hip_bfloat16* wOf = wTf + 18 * 4 * 64 * 8;          // 18*2*64*8 bf16

    int prep_total = 18 * 4 * 64 * 8 + 18 * 2 * 64 * 8 + 27;
    prep<<<(prep_total + 255) / 256, 256, 0, stream>>>(
        w_dcn, w_off, b_off, w_mask, b_mask, wTf, wOf, rebias);

    transpose_x<<<BB * 256, 256, 0, stream>>>(x, xt);

    offmask<<<BB * HH * 2, 256, 0, stream>>>(xt, wOf, rebias, off_out, mask_ws);

    deform<<<BB * HH * 2, 256, 0, stream>>>(xt, off_out, mask_ws, wTf, b_dcn, out);
}

// Round 5
// 75.461 us; speedup vs baseline: 10.4289x; 1.1048x over previous
//
#include <hip/hip_runtime.h>
#include <hip/hip_bf16.h>
#include <math.h>

#define BB 4
#define CC 64
#define OCN 64
#define HH 128
#define WW 128
#define HW (HH*WW)
#define KKN 9
#define CK 576            // C*KK, GEMM K
#define APAD 200          // LDS row stride (bf16) for accs tiles

typedef short short8 __attribute__((ext_vector_type(8)));
typedef float floatx4 __attribute__((ext_vector_type(4)));
typedef unsigned int uintx4 __attribute__((ext_vector_type(4)));

__device__ __forceinline__ float bf2f(__hip_bfloat16 h) {
    unsigned short u = *reinterpret_cast<unsigned short*>(&h);
    return __uint_as_float(((unsigned)u) << 16);
}
__device__ __forceinline__ short f2bfs(float f) {
    __hip_bfloat16 h = __float2bfloat16(f);
    return *reinterpret_cast<short*>(&h);
}
__device__ __forceinline__ uintx4 as_u4(short8 v) {
    union { short8 s; uintx4 u; } x; x.s = v; return x.u;
}
__device__ __forceinline__ float blo(unsigned d) { return __uint_as_float(d << 16); }
__device__ __forceinline__ float bhi(unsigned d) { return __uint_as_float(d & 0xffff0000u); }

// ---------------- prep: wTf (dcn B-frags), wOf (off/mask B-frags, 27->32 oc), rebias ----
// B-frag pack: frag[((s*NT+nt)*64+l)*8+j] = W[oc = nt*16+(l&15)][kk = s*32+((l>>4)<<3)+j]
// K-order: kk = ktap*64 + c (tap-major, matches gather LDS layout).
__global__ __launch_bounds__(256) void prep(
    const float* __restrict__ w_dcn, const float* __restrict__ w_off,
    const float* __restrict__ b_off, const float* __restrict__ w_mask,
    const float* __restrict__ b_mask,
    __hip_bfloat16* __restrict__ wTf, __hip_bfloat16* __restrict__ wOf,
    float* __restrict__ rebias)
{
    int i = blockIdx.x * 256 + threadIdx.x;
    if (i < 18 * 4 * 64 * 8) {                 // wTf: 18 K-steps x 4 oc-tiles
        int jj = i & 7;
        int l  = (i >> 3) & 63;
        int nt = (i >> 9) & 3;
        int s  = i >> 11;
        int oc = nt * 16 + (l & 15);
        int kk = s * 32 + ((l >> 4) << 3) + jj;
        int c  = kk & 63;
        int kt = kk >> 6;
        wTf[i] = __float2bfloat16(w_dcn[(oc * CC + c) * 9 + kt]);
    }
    int j = i - 18 * 4 * 64 * 8;
    if (j >= 0 && j < 18 * 2 * 64 * 8) {       // wOf: 18 K-steps x 2 oc-tiles (27 used)
        int jj = j & 7;
        int l  = (j >> 3) & 63;
        int nt = (j >> 9) & 1;
        int s  = j >> 10;
        int oc = nt * 16 + (l & 15);
        int kk = s * 32 + ((l >> 4) << 3) + jj;
        int c  = kk & 63;
        int kt = kk >> 6;
        float v = 0.0f;
        if (oc < 18)      v = w_off[(oc * CC + c) * 9 + kt];
        else if (oc < 27) v = w_mask[((oc - 18) * CC + c) * 9 + kt];
        wOf[j] = __float2bfloat16(v);
    }
    int r = j - 18 * 2 * 64 * 8;
    if (r >= 0 && r < 27) rebias[r] = (r < 18) ? b_off[r] : b_mask[r - 18];
}

// ---------------- transpose_x: x[b][c][h][w] f32 -> xt[b][h*w][c] bf16 ----------------
__global__ __launch_bounds__(256) void transpose_x(
    const float* __restrict__ x, __hip_bfloat16* __restrict__ xt)
{
    __shared__ float tile[64][65];
    int tid = threadIdx.x;
    int tpix = blockIdx.x & 255;
    int b    = blockIdx.x >> 8;
    int pixbase = tpix * 64;
    const float* xb = x + (size_t)b * CC * HW;
    int lanep = tid & 63;
    #pragma unroll
    for (int i = 0; i < 16; ++i) {
        int c = (tid >> 6) * 16 + i;
        tile[c][lanep] = xb[(size_t)c * HW + pixbase + lanep];
    }
    __syncthreads();
    __hip_bfloat16* xo = xt + ((size_t)b * HW + pixbase) * CC;
    #pragma unroll
    for (int i = 0; i < 8; ++i) {
        int idx = tid + i * 256;
        int pixl = idx >> 5, c2 = idx & 31;
        unsigned short lo = (unsigned short)(unsigned)f2bfs(tile[2 * c2][pixl]);
        unsigned short hi = (unsigned short)(unsigned)f2bfs(tile[2 * c2 + 1][pixl]);
        unsigned packed = lo | ((unsigned)hi << 16);
        *reinterpret_cast<unsigned*>(&xo[(size_t)pixl * CC + c2 * 2]) = packed;
    }
}

// ---------------- offmask: 3x3 conv as MFMA GEMM [64pix x 576] x [576 x 32] ------------
// block = 256 threads / 4 waves, 64 pixels (half row). wave = (oc-tile, pixel-half).
__global__ __launch_bounds__(256) void offmask(
    const __hip_bfloat16* __restrict__ xt,
    const __hip_bfloat16* __restrict__ wOf, const float* __restrict__ rebias,
    float* __restrict__ off_out, float* __restrict__ mask_out)
{
    __shared__ __align__(16) __hip_bfloat16 accs[64][APAD];   // 25600 B

    int tid  = threadIdx.x;
    int lane = tid & 63;
    int wv   = __builtin_amdgcn_readfirstlane(tid >> 6);
    int nt   = wv & 1;       // oc-tile
    int ph   = wv >> 1;      // pixel half

    int wo0 = (blockIdx.x & 1) * 64;
    int row = (blockIdx.x >> 1) & (HH - 1);
    int b   = blockIdx.x >> 8;

    floatx4 accv[2] = {{0,0,0,0},{0,0,0,0}};
    const __hip_bfloat16* xtb = xt + (size_t)b * HW * CC;
    const short8 zero8 = {0,0,0,0,0,0,0,0};
    int kreg = (lane >> 4) << 3;

    for (int chunk = 0; chunk < 3; ++chunk) {   // chunk = ky row of the 3x3
        int y = row + chunk - 1;
        bool yvalid = (unsigned)y < (unsigned)HH;
        short8 v[6];
        #pragma unroll
        for (int it = 0; it < 6; ++it) {
            int e = tid + it * 256;
            int pix  = e & 63;
            int rest = e >> 6;        // 0..23
            int kl   = rest >> 3;     // kx 0..2
            int c8   = rest & 7;
            int xw   = wo0 + pix + kl - 1;
            bool valid = yvalid && ((unsigned)xw < (unsigned)WW);
            v[it] = zero8;
            if (valid)
                v[it] = *reinterpret_cast<const short8*>(xtb + ((size_t)y * WW + xw) * CC + c8 * 8);
        }
        #pragma unroll
        for (int it = 0; it < 6; ++it) {
            int e = tid + it * 256;
            int pix  = e & 63;
            int rest = e >> 6;
            int kl   = rest >> 3;
            int c8   = rest & 7;
            *reinterpret_cast<short8*>(&accs[pix][kl * 64 + c8 * 8]) = v[it];
        }
        __syncthreads();

        #pragma unroll
        for (int step = 0; step < 6; ++step) {
            int s = chunk * 6 + step;
            short8 bfrag = *(reinterpret_cast<const short8*>(wOf) + (size_t)(s * 2 + nt) * 64 + lane);
            #pragma unroll
            for (int q = 0; q < 2; ++q) {
                int pg = ph * 2 + q;
                short8 a = *reinterpret_cast<const short8*>(&accs[pg * 16 + (lane & 15)][step * 32 + kreg]);
                accv[q] = __builtin_amdgcn_mfma_f32_16x16x32_bf16(a, bfrag, accv[q], 0, 0, 0);
            }
        }
        if (chunk < 2) __syncthreads();
    }

    // D layout: col = lane&15 (oc), row = (lane>>4)*4+reg (pixel) -> float4 stores
    int oc = nt * 16 + (lane & 15);
    #pragma unroll
    for (int q = 0; q < 2; ++q) {
        int pg = ph * 2 + q;
        int pcol = wo0 + pg * 16 + ((lane >> 4) << 2);
        if (oc < 18) {
            float bias = rebias[oc];
            floatx4 o = accv[q];
            o[0] += bias; o[1] += bias; o[2] += bias; o[3] += bias;
            *reinterpret_cast<floatx4*>(&off_out[(((size_t)b * 18 + oc) * HH + row) * WW + pcol]) = o;
        } else if (oc < 27) {
            float bias = rebias[oc];
            floatx4 o = accv[q];
            #pragma unroll
            for (int p = 0; p < 4; ++p) o[p] = 1.0f / (1.0f + expf(-(o[p] + bias)));
            *reinterpret_cast<floatx4*>(&mask_out[(((size_t)b * 9 + (oc - 18)) * HH + row) * WW + pcol]) = o;
        }
    }
}

// ---------------- deform: bilinear gather (rolling batches) + MFMA GEMM ----------------
// block = 256 threads / 4 waves, 64 pixels (half row). Gather: thread=(pix=lane, r0),
// per k-group loads taps for c8=r0 and r0+4. MFMA: wave = oc-tile, 4 pixel-groups.
__global__ __launch_bounds__(256, 4) void deform(
    const __hip_bfloat16* __restrict__ xt,
    const float* __restrict__ off, const float* __restrict__ mask,
    const __hip_bfloat16* __restrict__ wTf, const float* __restrict__ b_dcn,
    float* __restrict__ out)
{
    __shared__ __align__(16) __hip_bfloat16 accs[64][APAD];   // 25600 B
    __shared__ uintx4 tabs[KKN][64];                          // 9216 B (idx u16 | wt-bf16<<16, 4 taps)

    int tid  = threadIdx.x;
    int lane = tid & 63;
    int wv   = __builtin_amdgcn_readfirstlane(tid >> 6);
    int pix  = lane;
    int r0   = tid >> 6;          // c8a = r0, c8b = r0+4

    int wo0 = (blockIdx.x & 1) * 64;
    int row = (blockIdx.x >> 1) & (HH - 1);
    int b   = blockIdx.x >> 8;

    // phase 0: bilinear tap setup (9 k x 64 pixels), packed as uint4 per (k,pix)
    for (int e = tid; e < KKN * 64; e += 256) {
        int k = e >> 6, p = e & 63;
        int wo = wo0 + p;
        float dy = off[((b * 18 + 2 * k    ) * HH + row) * WW + wo];
        float dx = off[((b * 18 + 2 * k + 1) * HH + row) * WW + wo];
        float m  = mask[((b * 9 + k) * HH + row) * WW + wo];
        float py = dy + (float)(k / 3) + (float)(row - 1);
        float px = dx + (float)(k % 3) + (float)(wo - 1);
        float y0f = floorf(py), x0f = floorf(px);
        float ly = py - y0f, lx = px - x0f;
        int y0 = (int)y0f, x0 = (int)x0f;
        uintx4 rec;
        #pragma unroll
        for (int t = 0; t < 4; ++t) {
            int yi = y0 + (t >> 1), xi = x0 + (t & 1);
            float wy = (t >> 1) ? ly : 1.0f - ly;
            float wx = (t & 1)  ? lx : 1.0f - lx;
            bool valid = ((unsigned)yi < (unsigned)HH) && ((unsigned)xi < (unsigned)WW);
            int yc = min(max(yi, 0), HH - 1);
            int xc = min(max(xi, 0), WW - 1);
            __hip_bfloat16 hw = __float2bfloat16(valid ? wy * wx * m : 0.0f);
            unsigned short wb = *reinterpret_cast<unsigned short*>(&hw);
            rec[t] = (unsigned)(yc * WW + xc) | ((unsigned)wb << 16);
        }
        tabs[k][p] = rec;
    }
    __syncthreads();

    const char* xtb = (const char*)(xt + (size_t)b * HW * CC);
    int co_a = r0 * 16;            // c8a byte offset within a pixel's 128B channel row
    int co_b = r0 * 16 + 64;       // c8b

    short8 buf[2][8];
    uintx4 tb[2];
    floatx4 accv[4] = {{0,0,0,0},{0,0,0,0},{0,0,0,0},{0,0,0,0}};
    int kreg = (lane >> 4) << 3;

#define ISSUE(G9) do { \
    uintx4 _t = tabs[(G9)][pix]; \
    tb[(G9) & 1] = _t; \
    { unsigned _o = (_t[0] & 0xffffu) << 7; \
      buf[(G9) & 1][0] = *(const short8*)(xtb + _o + co_a); \
      buf[(G9) & 1][1] = *(const short8*)(xtb + _o + co_b); } \
    { unsigned _o = (_t[1] & 0xffffu) << 7; \
      buf[(G9) & 1][2] = *(const short8*)(xtb + _o + co_a); \
      buf[(G9) & 1][3] = *(const short8*)(xtb + _o + co_b); } \
    { unsigned _o = (_t[2] & 0xffffu) << 7; \
      buf[(G9) & 1][4] = *(const short8*)(xtb + _o + co_a); \
      buf[(G9) & 1][5] = *(const short8*)(xtb + _o + co_b); } \
    { unsigned _o = (_t[3] & 0xffffu) << 7; \
      buf[(G9) & 1][6] = *(const short8*)(xtb + _o + co_a); \
      buf[(G9) & 1][7] = *(const short8*)(xtb + _o + co_b); } \
} while (0)

#define COMBINE(G9) do { \
    float aA[8] = {0,0,0,0,0,0,0,0}; \
    float aB[8] = {0,0,0,0,0,0,0,0}; \
    _Pragma("unroll") \
    for (int t = 0; t < 4; ++t) { \
        float wt = __uint_as_float(tb[(G9) & 1][t] & 0xffff0000u); \
        uintx4 dA = as_u4(buf[(G9) & 1][2 * t]); \
        uintx4 dB = as_u4(buf[(G9) & 1][2 * t + 1]); \
        _Pragma("unroll") \
        for (int jq = 0; jq < 4; ++jq) { \
            aA[2 * jq]     = fmaf(wt, blo(dA[jq]), aA[2 * jq]); \
            aA[2 * jq + 1] = fmaf(wt, bhi(dA[jq]), aA[2 * jq + 1]); \
            aB[2 * jq]     = fmaf(wt, blo(dB[jq]), aB[2 * jq]); \
            aB[2 * jq + 1] = fmaf(wt, bhi(dB[jq]), aB[2 * jq + 1]); \
        } \
    } \
    short8 oA, oB; \
    _Pragma("unroll") \
    for (int jq = 0; jq < 8; ++jq) { oA[jq] = f2bfs(aA[jq]); oB[jq] = f2bfs(aB[jq]); } \
    *reinterpret_cast<short8*>(&accs[pix][((G9) % 3) * 64 + r0 * 8])      = oA; \
    *reinterpret_cast<short8*>(&accs[pix][((G9) % 3) * 64 + r0 * 8 + 32]) = oB; \
} while (0)

#define MFMA_CHUNK(CH) do { \
    _Pragma("unroll") \
    for (int step = 0; step < 6; ++step) { \
        int s = (CH) * 6 + step; \
        short8 bfrag = *(reinterpret_cast<const short8*>(wTf) + (size_t)(s * 4 + wv) * 64 + lane); \
        _Pragma("unroll") \
        for (int pg = 0; pg < 4; ++pg) { \
            short8 a = *reinterpret_cast<const short8*>(&accs[pg * 16 + (lane & 15)][step * 32 + kreg]); \
            accv[pg] = __builtin_amdgcn_mfma_f32_16x16x32_bf16(a, bfrag, accv[pg], 0, 0, 0); \
        } \
    } \
} while (0)

    ISSUE(0);
    // ---- chunk 0 ----
    ISSUE(1); COMBINE(0);
    ISSUE(2); COMBINE(1); COMBINE(2);
    __syncthreads();
    ISSUE(3);                       // prefetch chunk1 batch0, flies across MFMA+barrier
    MFMA_CHUNK(0);
    asm volatile("s_waitcnt lgkmcnt(0)" ::: "memory");
    __builtin_amdgcn_s_barrier();   // raw: does NOT drain vmcnt (keep prefetch in flight)
    // ---- chunk 1 ----
    ISSUE(4); COMBINE(3);
    ISSUE(5); COMBINE(4); COMBINE(5);
    __syncthreads();
    ISSUE(6);
    MFMA_CHUNK(1);
    asm volatile("s_waitcnt lgkmcnt(0)" ::: "memory");
    __builtin_amdgcn_s_barrier();
    // ---- chunk 2 ----
    ISSUE(7); COMBINE(6);
    ISSUE(8); COMBINE(7); COMBINE(8);
    __syncthreads();
    MFMA_CHUNK(2);

#undef ISSUE
#undef COMBINE
#undef MFMA_CHUNK

    // epilogue: wave wv owns oc-tile wv. D: col=lane&15 (oc), row=(lane>>4)*4+reg (pixel)
    int oc = wv * 16 + (lane & 15);
    float bias = b_dcn[oc];
    #pragma unroll
    for (int pg = 0; pg < 4; ++pg) {
        int pcol = wo0 + pg * 16 + ((lane >> 4) << 2);
        floatx4 o = accv[pg];
        o[0] += bias; o[1] += bias; o[2] += bias; o[3] += bias;
        *reinterpret_cast<floatx4*>(&out[(((size_t)b * OCN + oc) * HH + row) * WW + pcol]) = o;
    }
}

extern "C" void kernel_launch(void* const* d_in, const int* in_sizes, int n_in,
                              void* d_out, int out_size, void* d_ws, size_t ws_size,
                              hipStream_t stream) {
    const float* x      = (const float*)d_in[0];
    const float* w_off  = (const float*)d_in[1];
    const float* b_off  = (const float*)d_in[2];
    const float* w_mask = (const float*)d_in[3];
    const float* b_mask = (const float*)d_in[4];
    const float* w_dcn  = (const float*)d_in[5];
    const float* b_dcn  = (const float*)d_in[6];

    float* out     = (float*)d_out;                       // B*OC*H*W
    float* off_out = out + (size_t)BB * OCN * HW;         // B*18*H*W (output 1)

    float* mask_ws = (float*)d_ws;                        // B*9*H*W f32
    float* rebias  = mask_ws + (size_t)BB * 9 * HW;       // 32 f32 (padded)
    __hip_bfloat16* xt  = (__hip_bfloat16*)(rebias + 32); // B*HW*C bf16
    __hip_bfloat16* wTf = xt + (size_t)BB * HW * CC;      // 18*4*64*8 bf16
    __hip_bfloat16* wOf = wTf + 18 * 4 * 64 * 8;          // 18*2*64*8 bf16

    int prep_total = 18 * 4 * 64 * 8 + 18 * 2 * 64 * 8 + 27;
    prep<<<(prep_total + 255) / 256, 256, 0, stream>>>(
        w_dcn, w_off, b_off, w_mask, b_mask, wTf, wOf, rebias);

    transpose_x<<<BB * 256, 256, 0, stream>>>(x, xt);

    offmask<<<BB * HH * 2, 256, 0, stream>>>(xt, wOf, rebias, off_out, mask_ws);

    deform<<<BB * HH * 2, 256, 0, stream>>>(xt, off_out, mask_ws, wTf, b_dcn, out);
}

// Round 6
// 74.334 us; speedup vs baseline: 10.5870x; 1.0152x over previous
//
#include <hip/hip_runtime.h>
#include <hip/hip_bf16.h>
#include <math.h>

#define BB 4
#define CC 64
#define OCN 64
#define HH 128
#define WW 128
#define HW (HH*WW)
#define KKN 9
#define CK 576            // C*KK, GEMM K
#define APAD 200          // LDS row stride (bf16) for accs tiles

typedef short short8 __attribute__((ext_vector_type(8)));
typedef float floatx4 __attribute__((ext_vector_type(4)));
typedef unsigned int uintx4 __attribute__((ext_vector_type(4)));

__device__ __forceinline__ float bf2f(__hip_bfloat16 h) {
    unsigned short u = *reinterpret_cast<unsigned short*>(&h);
    return __uint_as_float(((unsigned)u) << 16);
}
__device__ __forceinline__ short f2bfs(float f) {
    __hip_bfloat16 h = __float2bfloat16(f);
    return *reinterpret_cast<short*>(&h);
}
__device__ __forceinline__ uintx4 as_u4(short8 v) {
    union { short8 s; uintx4 u; } x; x.s = v; return x.u;
}
__device__ __forceinline__ float blo(unsigned d) { return __uint_as_float(d << 16); }
__device__ __forceinline__ float bhi(unsigned d) { return __uint_as_float(d & 0xffff0000u); }

// ---------------- prep: wTf (dcn B-frags), wOf (off/mask B-frags, 27->32 oc), rebias ----
// B-frag pack: frag[((s*NT+nt)*64+l)*8+j] = W[oc = nt*16+(l&15)][kk = s*32+((l>>4)<<3)+j]
// K-order: kk = ktap*64 + c (tap-major, matches gather LDS layout).
__global__ __launch_bounds__(256) void prep(
    const float* __restrict__ w_dcn, const float* __restrict__ w_off,
    const float* __restrict__ b_off, const float* __restrict__ w_mask,
    const float* __restrict__ b_mask,
    __hip_bfloat16* __restrict__ wTf, __hip_bfloat16* __restrict__ wOf,
    float* __restrict__ rebias)
{
    int i = blockIdx.x * 256 + threadIdx.x;
    if (i < 18 * 4 * 64 * 8) {                 // wTf: 18 K-steps x 4 oc-tiles
        int jj = i & 7;
        int l  = (i >> 3) & 63;
        int nt = (i >> 9) & 3;
        int s  = i >> 11;
        int oc = nt * 16 + (l & 15);
        int kk = s * 32 + ((l >> 4) << 3) + jj;
        int c  = kk & 63;
        int kt = kk >> 6;
        wTf[i] = __float2bfloat16(w_dcn[(oc * CC + c) * 9 + kt]);
    }
    int j = i - 18 * 4 * 64 * 8;
    if (j >= 0 && j < 18 * 2 * 64 * 8) {       // wOf: 18 K-steps x 2 oc-tiles (27 used)
        int jj = j & 7;
        int l  = (j >> 3) & 63;
        int nt = (j >> 9) & 1;
        int s  = j >> 10;
        int oc = nt * 16 + (l & 15);
        int kk = s * 32 + ((l >> 4) << 3) + jj;
        int c  = kk & 63;
        int kt = kk >> 6;
        float v = 0.0f;
        if (oc < 18)      v = w_off[(oc * CC + c) * 9 + kt];
        else if (oc < 27) v = w_mask[((oc - 18) * CC + c) * 9 + kt];
        wOf[j] = __float2bfloat16(v);
    }
    int r = j - 18 * 2 * 64 * 8;
    if (r >= 0 && r < 27) rebias[r] = (r < 18) ? b_off[r] : b_mask[r - 18];
}

// ---------------- transpose_x: x[b][c][h][w] f32 -> xt[b][h*w][c] bf16 ----------------
// 32 pixels/block, grid = B*512 = 2048.
__global__ __launch_bounds__(256) void transpose_x(
    const float* __restrict__ x, __hip_bfloat16* __restrict__ xt)
{
    __shared__ float tile[64][33];    // 8448 B
    int tid = threadIdx.x;
    int pixbase = (blockIdx.x & 511) * 32;
    int b       = blockIdx.x >> 9;
    const float* xb = x + (size_t)b * CC * HW;
    int p = tid & 31;
    #pragma unroll
    for (int i = 0; i < 8; ++i) {
        int c = (tid >> 5) * 8 + i;
        tile[c][p] = xb[(size_t)c * HW + pixbase + p];
    }
    __syncthreads();
    __hip_bfloat16* xo = xt + ((size_t)b * HW + pixbase) * CC;
    #pragma unroll
    for (int i = 0; i < 4; ++i) {
        int idx = tid + i * 256;
        int pixl = idx >> 5, c2 = idx & 31;
        unsigned short lo = (unsigned short)(unsigned)f2bfs(tile[2 * c2][pixl]);
        unsigned short hi = (unsigned short)(unsigned)f2bfs(tile[2 * c2 + 1][pixl]);
        unsigned packed = lo | ((unsigned)hi << 16);
        *reinterpret_cast<unsigned*>(&xo[(size_t)pixl * CC + c2 * 2]) = packed;
    }
}

// ---------------- offmask: 3x3 conv as MFMA GEMM [32pix x 576] x [576 x 32] ------------
// 32 pixels/block, grid 2048. wave = (oc-tile nt, pixel-group pg); 18 MFMA/wave.
__global__ __launch_bounds__(256, 8) void offmask(
    const __hip_bfloat16* __restrict__ xt,
    const __hip_bfloat16* __restrict__ wOf, const float* __restrict__ rebias,
    float* __restrict__ off_out, float* __restrict__ mask_out)
{
    __shared__ __align__(16) __hip_bfloat16 accs[32][APAD];   // 12800 B

    int tid  = threadIdx.x;
    int lane = tid & 63;
    int wv   = __builtin_amdgcn_readfirstlane(tid >> 6);
    int nt   = wv & 1;       // oc-tile
    int pg   = wv >> 1;      // pixel group

    int wo0 = (blockIdx.x & 3) * 32;
    int row = (blockIdx.x >> 2) & (HH - 1);
    int b   = blockIdx.x >> 9;

    floatx4 accv = {0, 0, 0, 0};
    const __hip_bfloat16* xtb = xt + (size_t)b * HW * CC;
    const short8 zero8 = {0,0,0,0,0,0,0,0};
    int kreg = (lane >> 4) << 3;

    for (int chunk = 0; chunk < 3; ++chunk) {   // chunk = ky row of the 3x3
        int y = row + chunk - 1;
        bool yvalid = (unsigned)y < (unsigned)HH;
        short8 v[3];
        #pragma unroll
        for (int it = 0; it < 3; ++it) {
            int e = tid + it * 256;
            int pix  = e & 31;
            int rest = e >> 5;        // 0..23
            int kl   = rest >> 3;     // kx 0..2
            int c8   = rest & 7;
            int xw   = wo0 + pix + kl - 1;
            bool valid = yvalid && ((unsigned)xw < (unsigned)WW);
            v[it] = zero8;
            if (valid)
                v[it] = *reinterpret_cast<const short8*>(xtb + ((size_t)y * WW + xw) * CC + c8 * 8);
        }
        #pragma unroll
        for (int it = 0; it < 3; ++it) {
            int e = tid + it * 256;
            int pix  = e & 31;
            int rest = e >> 5;
            int kl   = rest >> 3;
            int c8   = rest & 7;
            *reinterpret_cast<short8*>(&accs[pix][kl * 64 + c8 * 8]) = v[it];
        }
        __syncthreads();

        #pragma unroll
        for (int step = 0; step < 6; ++step) {
            int s = chunk * 6 + step;
            short8 bfrag = *(reinterpret_cast<const short8*>(wOf) + (size_t)(s * 2 + nt) * 64 + lane);
            short8 a = *reinterpret_cast<const short8*>(&accs[pg * 16 + (lane & 15)][step * 32 + kreg]);
            accv = __builtin_amdgcn_mfma_f32_16x16x32_bf16(a, bfrag, accv, 0, 0, 0);
        }
        if (chunk < 2) __syncthreads();
    }

    // D layout: col = lane&15 (oc), row = (lane>>4)*4+reg (pixel) -> float4 stores
    int oc = nt * 16 + (lane & 15);
    int pcol = wo0 + pg * 16 + ((lane >> 4) << 2);
    if (oc < 18) {
        float bias = rebias[oc];
        floatx4 o = accv;
        o[0] += bias; o[1] += bias; o[2] += bias; o[3] += bias;
        *reinterpret_cast<floatx4*>(&off_out[(((size_t)b * 18 + oc) * HH + row) * WW + pcol]) = o;
    } else if (oc < 27) {
        float bias = rebias[oc];
        floatx4 o = accv;
        #pragma unroll
        for (int q = 0; q < 4; ++q) o[q] = 1.0f / (1.0f + expf(-(o[q] + bias)));
        *reinterpret_cast<floatx4*>(&mask_out[(((size_t)b * 9 + (oc - 18)) * HH + row) * WW + pcol]) = o;
    }
}

// ---------------- deform: bilinear gather (rolling batches) + MFMA GEMM ----------------
// 32 pixels/block, grid 2048. Gather thread = (c8 = tid>>5, pix = tid&31): per k-group
// 4 tap loads (16B) double-buffered. MFMA: wave = oc-tile, 2 pixel-groups.
__global__ __launch_bounds__(256, 8) void deform(
    const __hip_bfloat16* __restrict__ xt,
    const float* __restrict__ off, const float* __restrict__ mask,
    const __hip_bfloat16* __restrict__ wTf, const float* __restrict__ b_dcn,
    float* __restrict__ out)
{
    __shared__ __align__(16) __hip_bfloat16 accs[32][APAD];   // 12800 B
    __shared__ uintx4 tabs[KKN][32];                          // 4608 B (idx u16 | wt-bf16<<16, 4 taps)

    int tid  = threadIdx.x;
    int lane = tid & 63;
    int wv   = __builtin_amdgcn_readfirstlane(tid >> 6);
    int pix  = tid & 31;
    int c8   = tid >> 5;          // 0..7

    int wo0 = (blockIdx.x & 3) * 32;
    int row = (blockIdx.x >> 2) & (HH - 1);
    int b   = blockIdx.x >> 9;

    // phase 0: bilinear tap setup (9 k x 32 pixels), packed as uint4 per (k,pix)
    for (int e = tid; e < KKN * 32; e += 256) {
        int k = e >> 5, p = e & 31;
        int wo = wo0 + p;
        float dy = off[((b * 18 + 2 * k    ) * HH + row) * WW + wo];
        float dx = off[((b * 18 + 2 * k + 1) * HH + row) * WW + wo];
        float m  = mask[((b * 9 + k) * HH + row) * WW + wo];
        float py = dy + (float)(k / 3) + (float)(row - 1);
        float px = dx + (float)(k % 3) + (float)(wo - 1);
        float y0f = floorf(py), x0f = floorf(px);
        float ly = py - y0f, lx = px - x0f;
        int y0 = (int)y0f, x0 = (int)x0f;
        uintx4 rec;
        #pragma unroll
        for (int t = 0; t < 4; ++t) {
            int yi = y0 + (t >> 1), xi = x0 + (t & 1);
            float wy = (t >> 1) ? ly : 1.0f - ly;
            float wx = (t & 1)  ? lx : 1.0f - lx;
            bool valid = ((unsigned)yi < (unsigned)HH) && ((unsigned)xi < (unsigned)WW);
            int yc = min(max(yi, 0), HH - 1);
            int xc = min(max(xi, 0), WW - 1);
            __hip_bfloat16 hw = __float2bfloat16(valid ? wy * wx * m : 0.0f);
            unsigned short wb = *reinterpret_cast<unsigned short*>(&hw);
            rec[t] = (unsigned)(yc * WW + xc) | ((unsigned)wb << 16);
        }
        tabs[k][p] = rec;
    }
    __syncthreads();

    const char* xtb = (const char*)(xt + (size_t)b * HW * CC);
    int co = c8 * 16;             // byte offset of this thread's 8 channels

    short8 buf[2][4];
    uintx4 tb[2];
    floatx4 accv[2] = {{0,0,0,0},{0,0,0,0}};
    int kreg = (lane >> 4) << 3;

#define ISSUE(G9) do { \
    uintx4 _t = tabs[(G9)][pix]; \
    tb[(G9) & 1] = _t; \
    buf[(G9) & 1][0] = *(const short8*)(xtb + ((_t[0] & 0xffffu) << 7) + co); \
    buf[(G9) & 1][1] = *(const short8*)(xtb + ((_t[1] & 0xffffu) << 7) + co); \
    buf[(G9) & 1][2] = *(const short8*)(xtb + ((_t[2] & 0xffffu) << 7) + co); \
    buf[(G9) & 1][3] = *(const short8*)(xtb + ((_t[3] & 0xffffu) << 7) + co); \
} while (0)

#define COMBINE(G9) do { \
    float aA[8] = {0,0,0,0,0,0,0,0}; \
    _Pragma("unroll") \
    for (int t = 0; t < 4; ++t) { \
        float wt = __uint_as_float(tb[(G9) & 1][t] & 0xffff0000u); \
        uintx4 dA = as_u4(buf[(G9) & 1][t]); \
        _Pragma("unroll") \
        for (int jq = 0; jq < 4; ++jq) { \
            aA[2 * jq]     = fmaf(wt, blo(dA[jq]), aA[2 * jq]); \
            aA[2 * jq + 1] = fmaf(wt, bhi(dA[jq]), aA[2 * jq + 1]); \
        } \
    } \
    short8 oA; \
    _Pragma("unroll") \
    for (int jq = 0; jq < 8; ++jq) { oA[jq] = f2bfs(aA[jq]); } \
    *reinterpret_cast<short8*>(&accs[pix][((G9) % 3) * 64 + c8 * 8]) = oA; \
} while (0)

#define MFMA_CHUNK(CH) do { \
    _Pragma("unroll") \
    for (int step = 0; step < 6; ++step) { \
        int s = (CH) * 6 + step; \
        short8 bfrag = *(reinterpret_cast<const short8*>(wTf) + (size_t)(s * 4 + wv) * 64 + lane); \
        _Pragma("unroll") \
        for (int pg = 0; pg < 2; ++pg) { \
            short8 a = *reinterpret_cast<const short8*>(&accs[pg * 16 + (lane & 15)][step * 32 + kreg]); \
            accv[pg] = __builtin_amdgcn_mfma_f32_16x16x32_bf16(a, bfrag, accv[pg], 0, 0, 0); \
        } \
    } \
} while (0)

    ISSUE(0);
    // ---- chunk 0 ----
    ISSUE(1); COMBINE(0);
    ISSUE(2); COMBINE(1); COMBINE(2);
    __syncthreads();
    ISSUE(3);                       // prefetch chunk1 batch0, flies across MFMA+barrier
    MFMA_CHUNK(0);
    asm volatile("s_waitcnt lgkmcnt(0)" ::: "memory");
    __builtin_amdgcn_s_barrier();   // raw: does NOT drain vmcnt (keep prefetch in flight)
    // ---- chunk 1 ----
    ISSUE(4); COMBINE(3);
    ISSUE(5); COMBINE(4); COMBINE(5);
    __syncthreads();
    ISSUE(6);
    MFMA_CHUNK(1);
    asm volatile("s_waitcnt lgkmcnt(0)" ::: "memory");
    __builtin_amdgcn_s_barrier();
    // ---- chunk 2 ----
    ISSUE(7); COMBINE(6);
    ISSUE(8); COMBINE(7); COMBINE(8);
    __syncthreads();
    MFMA_CHUNK(2);

#undef ISSUE
#undef COMBINE
#undef MFMA_CHUNK

    // epilogue: wave wv owns oc-tile wv. D: col=lane&15 (oc), row=(lane>>4)*4+reg (pixel)
    int oc = wv * 16 + (lane & 15);
    float bias = b_dcn[oc];
    #pragma unroll
    for (int pg = 0; pg < 2; ++pg) {
        int pcol = wo0 + pg * 16 + ((lane >> 4) << 2);
        floatx4 o = accv[pg];
        o[0] += bias; o[1] += bias; o[2] += bias; o[3] += bias;
        *reinterpret_cast<floatx4*>(&out[(((size_t)b * OCN + oc) * HH + row) * WW + pcol]) = o;
    }
}

extern "C" void kernel_launch(void* const* d_in, const int* in_sizes, int n_in,
                              void* d_out, int out_size, void* d_ws, size_t ws_size,
                              hipStream_t stream) {
    const float* x      = (const float*)d_in[0];
    const float* w_off  = (const float*)d_in[1];
    const float* b_off  = (const float*)d_in[2];
    const float* w_mask = (const float*)d_in[3];
    const float* b_mask = (const float*)d_in[4];
    const float* w_dcn  = (const float*)d_in[5];
    const float* b_dcn  = (const float*)d_in[6];

    float* out     = (float*)d_out;                       // B*OC*H*W
    float* off_out = out + (size_t)BB * OCN * HW;         // B*18*H*W (output 1)

    float* mask_ws = (float*)d_ws;                        // B*9*H*W f32
    float* rebias  = mask_ws + (size_t)BB * 9 * HW;       // 32 f32 (padded)
    __hip_bfloat16* xt  = (__hip_bfloat16*)(rebias + 32); // B*HW*C bf16
    __hip_bfloat16* wTf = xt + (size_t)BB * HW * CC;      // 18*4*64*8 bf16
    __hip_bfloat16* wOf = wTf + 18 * 4 * 64 * 8;          // 18*2*64*8 bf16

    int prep_total = 18 * 4 * 64 * 8 + 18 * 2 * 64 * 8 + 27;
    prep<<<(prep_total + 255) / 256, 256, 0, stream>>>(
        w_dcn, w_off, b_off, w_mask, b_mask, wTf, wOf, rebias);

    transpose_x<<<BB * 512, 256, 0, stream>>>(x, xt);

    offmask<<<BB * HH * 4, 256, 0, stream>>>(xt, wOf, rebias, off_out, mask_ws);

    deform<<<BB * HH * 4, 256, 0, stream>>>(xt, off_out, mask_ws, wTf, b_dcn, out);
}

// Round 7
// 44.641 us; speedup vs baseline: 17.6293x; 1.6652x over previous
//
#include <hip/hip_runtime.h>
#include <hip/hip_bf16.h>
#include <math.h>

#define BB 4
#define CC 64
#define OCN 64
#define HH 128
#define WW 128
#define HW (HH*WW)
#define KKN 9
#define CK 576            // C*KK, GEMM K
#define APAD 200          // LDS row stride (bf16) for accs tiles

typedef short short8 __attribute__((ext_vector_type(8)));
typedef float floatx4 __attribute__((ext_vector_type(4)));
typedef unsigned int uintx4 __attribute__((ext_vector_type(4)));

__device__ __forceinline__ float bf2f(__hip_bfloat16 h) {
    unsigned short u = *reinterpret_cast<unsigned short*>(&h);
    return __uint_as_float(((unsigned)u) << 16);
}
__device__ __forceinline__ short f2bfs(float f) {
    __hip_bfloat16 h = __float2bfloat16(f);
    return *reinterpret_cast<short*>(&h);
}
__device__ __forceinline__ uintx4 as_u4(short8 v) {
    union { short8 s; uintx4 u; } x; x.s = v; return x.u;
}
__device__ __forceinline__ float blo(unsigned d) { return __uint_as_float(d << 16); }
__device__ __forceinline__ float bhi(unsigned d) { return __uint_as_float(d & 0xffff0000u); }

// ---------------- transpose_prep: xt transpose + weight fragment packing, fused -------
// blocks [0, BB*512): transpose 32 pixels each. blocks [BB*512, +217): prep.
// B-frag pack: frag[((s*NT+nt)*64+l)*8+j] = W[oc = nt*16+(l&15)][kk = s*32+((l>>4)<<3)+j]
// K-order: kk = ktap*64 + c (tap-major, matches gather LDS layout).
__global__ __launch_bounds__(256) void transpose_prep(
    const float* __restrict__ x,
    const float* __restrict__ w_dcn, const float* __restrict__ w_off,
    const float* __restrict__ b_off, const float* __restrict__ w_mask,
    const float* __restrict__ b_mask,
    __hip_bfloat16* __restrict__ xt, __hip_bfloat16* __restrict__ wTf,
    __hip_bfloat16* __restrict__ wOf, float* __restrict__ rebias)
{
    int blk = blockIdx.x;
    int tid = threadIdx.x;
    if (blk < BB * 512) {
        __shared__ float tile[64][33];    // 8448 B
        int pixbase = (blk & 511) * 32;
        int b       = blk >> 9;
        const float* xb = x + (size_t)b * CC * HW;
        int p = tid & 31;
        #pragma unroll
        for (int i = 0; i < 8; ++i) {
            int c = (tid >> 5) * 8 + i;
            tile[c][p] = xb[(size_t)c * HW + pixbase + p];
        }
        __syncthreads();
        __hip_bfloat16* xo = xt + ((size_t)b * HW + pixbase) * CC;
        #pragma unroll
        for (int i = 0; i < 4; ++i) {
            int idx = tid + i * 256;
            int pixl = idx >> 5, c2 = idx & 31;
            unsigned short lo = (unsigned short)(unsigned)f2bfs(tile[2 * c2][pixl]);
            unsigned short hi = (unsigned short)(unsigned)f2bfs(tile[2 * c2 + 1][pixl]);
            unsigned packed = lo | ((unsigned)hi << 16);
            *reinterpret_cast<unsigned*>(&xo[(size_t)pixl * CC + c2 * 2]) = packed;
        }
        return;
    }
    int i = (blk - BB * 512) * 256 + tid;
    if (i < 18 * 4 * 64 * 8) {                 // wTf: 18 K-steps x 4 oc-tiles
        int jj = i & 7;
        int l  = (i >> 3) & 63;
        int nt = (i >> 9) & 3;
        int s  = i >> 11;
        int oc = nt * 16 + (l & 15);
        int kk = s * 32 + ((l >> 4) << 3) + jj;
        int c  = kk & 63;
        int kt = kk >> 6;
        wTf[i] = __float2bfloat16(w_dcn[(oc * CC + c) * 9 + kt]);
    }
    int j = i - 18 * 4 * 64 * 8;
    if (j >= 0 && j < 18 * 2 * 64 * 8) {       // wOf: 18 K-steps x 2 oc-tiles (27 used)
        int jj = j & 7;
        int l  = (j >> 3) & 63;
        int nt = (j >> 9) & 1;
        int s  = j >> 10;
        int oc = nt * 16 + (l & 15);
        int kk = s * 32 + ((l >> 4) << 3) + jj;
        int c  = kk & 63;
        int kt = kk >> 6;
        float v = 0.0f;
        if (oc < 18)      v = w_off[(oc * CC + c) * 9 + kt];
        else if (oc < 27) v = w_mask[((oc - 18) * CC + c) * 9 + kt];
        wOf[j] = __float2bfloat16(v);
    }
    int r = j - 18 * 2 * 64 * 8;
    if (r >= 0 && r < 27) rebias[r] = (r < 18) ? b_off[r] : b_mask[r - 18];
}

// ---------------- offmask: 3x3 conv as MFMA GEMM [32pix x 576] x [576 x 32] ------------
// 32 pixels/block, grid 2048. Staging: c8 = tid&7, pix = (tid>>3)&31 -> 8 lanes share a
// 128B line. wave = (oc-tile nt, pixel-group pg); 18 MFMA/wave.
__global__ __launch_bounds__(256, 8) void offmask(
    const __hip_bfloat16* __restrict__ xt,
    const __hip_bfloat16* __restrict__ wOf, const float* __restrict__ rebias,
    float* __restrict__ off_out, float* __restrict__ mask_out)
{
    __shared__ __align__(16) __hip_bfloat16 accs[32][APAD];   // 12800 B

    int tid  = threadIdx.x;
    int lane = tid & 63;
    int wv   = __builtin_amdgcn_readfirstlane(tid >> 6);
    int nt   = wv & 1;       // oc-tile
    int pg   = wv >> 1;      // pixel group
    int c8   = tid & 7;
    int spix = (tid >> 3) & 31;

    int wo0 = (blockIdx.x & 3) * 32;
    int row = (blockIdx.x >> 2) & (HH - 1);
    int b   = blockIdx.x >> 9;

    floatx4 accv = {0, 0, 0, 0};
    const __hip_bfloat16* xtb = xt + (size_t)b * HW * CC;
    const short8 zero8 = {0,0,0,0,0,0,0,0};
    int kreg = (lane >> 4) << 3;

    for (int chunk = 0; chunk < 3; ++chunk) {   // chunk = ky row of the 3x3
        int y = row + chunk - 1;
        bool yvalid = (unsigned)y < (unsigned)HH;
        short8 v[3];
        #pragma unroll
        for (int kl = 0; kl < 3; ++kl) {
            int xw = wo0 + spix + kl - 1;
            bool valid = yvalid && ((unsigned)xw < (unsigned)WW);
            v[kl] = zero8;
            if (valid)
                v[kl] = *reinterpret_cast<const short8*>(xtb + ((size_t)y * WW + xw) * CC + c8 * 8);
        }
        #pragma unroll
        for (int kl = 0; kl < 3; ++kl)
            *reinterpret_cast<short8*>(&accs[spix][kl * 64 + c8 * 8]) = v[kl];
        __syncthreads();

        #pragma unroll
        for (int step = 0; step < 6; ++step) {
            int s = chunk * 6 + step;
            short8 bfrag = *(reinterpret_cast<const short8*>(wOf) + (size_t)(s * 2 + nt) * 64 + lane);
            short8 a = *reinterpret_cast<const short8*>(&accs[pg * 16 + (lane & 15)][step * 32 + kreg]);
            accv = __builtin_amdgcn_mfma_f32_16x16x32_bf16(a, bfrag, accv, 0, 0, 0);
        }
        if (chunk < 2) __syncthreads();
    }

    // D layout: col = lane&15 (oc), row = (lane>>4)*4+reg (pixel) -> float4 stores
    int oc = nt * 16 + (lane & 15);
    int pcol = wo0 + pg * 16 + ((lane >> 4) << 2);
    if (oc < 18) {
        float bias = rebias[oc];
        floatx4 o = accv;
        o[0] += bias; o[1] += bias; o[2] += bias; o[3] += bias;
        *reinterpret_cast<floatx4*>(&off_out[(((size_t)b * 18 + oc) * HH + row) * WW + pcol]) = o;
    } else if (oc < 27) {
        float bias = rebias[oc];
        floatx4 o = accv;
        #pragma unroll
        for (int q = 0; q < 4; ++q) o[q] = 1.0f / (1.0f + expf(-(o[q] + bias)));
        *reinterpret_cast<floatx4*>(&mask_out[(((size_t)b * 9 + (oc - 18)) * HH + row) * WW + pcol]) = o;
    }
}

// ---------------- deform: bilinear gather (rolling batches) + MFMA GEMM ----------------
// 32 pixels/block, grid 2048. Gather thread = (pix = tid>>3, c8 = tid&7): lanes 0-7 read
// one 128B line per tap. MFMA: wave = oc-tile, 2 pixel-groups.
__global__ __launch_bounds__(256, 8) void deform(
    const __hip_bfloat16* __restrict__ xt,
    const float* __restrict__ off, const float* __restrict__ mask,
    const __hip_bfloat16* __restrict__ wTf, const float* __restrict__ b_dcn,
    float* __restrict__ out)
{
    __shared__ __align__(16) __hip_bfloat16 accs[32][APAD];   // 12800 B
    __shared__ uintx4 tabs[KKN][32];                          // 4608 B (idx u16 | wt-bf16<<16, 4 taps)

    int tid  = threadIdx.x;
    int lane = tid & 63;
    int wv   = __builtin_amdgcn_readfirstlane(tid >> 6);
    int pix  = tid >> 3;          // 0..31
    int c8   = tid & 7;           // 0..7

    int wo0 = (blockIdx.x & 3) * 32;
    int row = (blockIdx.x >> 2) & (HH - 1);
    int b   = blockIdx.x >> 9;

    // phase 0: bilinear tap setup (9 k x 32 pixels), packed as uint4 per (k,pix)
    for (int e = tid; e < KKN * 32; e += 256) {
        int k = e >> 5, p = e & 31;
        int wo = wo0 + p;
        float dy = off[((b * 18 + 2 * k    ) * HH + row) * WW + wo];
        float dx = off[((b * 18 + 2 * k + 1) * HH + row) * WW + wo];
        float m  = mask[((b * 9 + k) * HH + row) * WW + wo];
        float py = dy + (float)(k / 3) + (float)(row - 1);
        float px = dx + (float)(k % 3) + (float)(wo - 1);
        float y0f = floorf(py), x0f = floorf(px);
        float ly = py - y0f, lx = px - x0f;
        int y0 = (int)y0f, x0 = (int)x0f;
        uintx4 rec;
        #pragma unroll
        for (int t = 0; t < 4; ++t) {
            int yi = y0 + (t >> 1), xi = x0 + (t & 1);
            float wy = (t >> 1) ? ly : 1.0f - ly;
            float wx = (t & 1)  ? lx : 1.0f - lx;
            bool valid = ((unsigned)yi < (unsigned)HH) && ((unsigned)xi < (unsigned)WW);
            int yc = min(max(yi, 0), HH - 1);
            int xc = min(max(xi, 0), WW - 1);
            __hip_bfloat16 hw = __float2bfloat16(valid ? wy * wx * m : 0.0f);
            unsigned short wb = *reinterpret_cast<unsigned short*>(&hw);
            rec[t] = (unsigned)(yc * WW + xc) | ((unsigned)wb << 16);
        }
        tabs[k][p] = rec;
    }
    __syncthreads();

    const char* xtb = (const char*)(xt + (size_t)b * HW * CC);
    int co = c8 * 16;             // byte offset of this thread's 8 channels

    short8 buf[2][4];
    uintx4 tb[2];
    floatx4 accv[2] = {{0,0,0,0},{0,0,0,0}};
    int kreg = (lane >> 4) << 3;

#define ISSUE(G9) do { \
    uintx4 _t = tabs[(G9)][pix]; \
    tb[(G9) & 1] = _t; \
    buf[(G9) & 1][0] = *(const short8*)(xtb + ((_t[0] & 0xffffu) << 7) + co); \
    buf[(G9) & 1][1] = *(const short8*)(xtb + ((_t[1] & 0xffffu) << 7) + co); \
    buf[(G9) & 1][2] = *(const short8*)(xtb + ((_t[2] & 0xffffu) << 7) + co); \
    buf[(G9) & 1][3] = *(const short8*)(xtb + ((_t[3] & 0xffffu) << 7) + co); \
} while (0)

#define COMBINE(G9) do { \
    float aA[8] = {0,0,0,0,0,0,0,0}; \
    _Pragma("unroll") \
    for (int t = 0; t < 4; ++t) { \
        float wt = __uint_as_float(tb[(G9) & 1][t] & 0xffff0000u); \
        uintx4 dA = as_u4(buf[(G9) & 1][t]); \
        _Pragma("unroll") \
        for (int jq = 0; jq < 4; ++jq) { \
            aA[2 * jq]     = fmaf(wt, blo(dA[jq]), aA[2 * jq]); \
            aA[2 * jq + 1] = fmaf(wt, bhi(dA[jq]), aA[2 * jq + 1]); \
        } \
    } \
    short8 oA; \
    _Pragma("unroll") \
    for (int jq = 0; jq < 8; ++jq) { oA[jq] = f2bfs(aA[jq]); } \
    *reinterpret_cast<short8*>(&accs[pix][((G9) % 3) * 64 + c8 * 8]) = oA; \
} while (0)

#define MFMA_CHUNK(CH) do { \
    _Pragma("unroll") \
    for (int step = 0; step < 6; ++step) { \
        int s = (CH) * 6 + step; \
        short8 bfrag = *(reinterpret_cast<const short8*>(wTf) + (size_t)(s * 4 + wv) * 64 + lane); \
        _Pragma("unroll") \
        for (int pg = 0; pg < 2; ++pg) { \
            short8 a = *reinterpret_cast<const short8*>(&accs[pg * 16 + (lane & 15)][step * 32 + kreg]); \
            accv[pg] = __builtin_amdgcn_mfma_f32_16x16x32_bf16(a, bfrag, accv[pg], 0, 0, 0); \
        } \
    } \
} while (0)

    ISSUE(0);
    // ---- chunk 0 ----
    ISSUE(1); COMBINE(0);
    ISSUE(2); COMBINE(1); COMBINE(2);
    __syncthreads();
    ISSUE(3);                       // prefetch chunk1 batch0, flies across MFMA+barrier
    MFMA_CHUNK(0);
    asm volatile("s_waitcnt lgkmcnt(0)" ::: "memory");
    __builtin_amdgcn_s_barrier();   // raw: does NOT drain vmcnt (keep prefetch in flight)
    // ---- chunk 1 ----
    ISSUE(4); COMBINE(3);
    ISSUE(5); COMBINE(4); COMBINE(5);
    __syncthreads();
    ISSUE(6);
    MFMA_CHUNK(1);
    asm volatile("s_waitcnt lgkmcnt(0)" ::: "memory");
    __builtin_amdgcn_s_barrier();
    // ---- chunk 2 ----
    ISSUE(7); COMBINE(6);
    ISSUE(8); COMBINE(7); COMBINE(8);
    __syncthreads();
    MFMA_CHUNK(2);

#undef ISSUE
#undef COMBINE
#undef MFMA_CHUNK

    // epilogue: wave wv owns oc-tile wv. D: col=lane&15 (oc), row=(lane>>4)*4+reg (pixel)
    int oc = wv * 16 + (lane & 15);
    float bias = b_dcn[oc];
    #pragma unroll
    for (int pg = 0; pg < 2; ++pg) {
        int pcol = wo0 + pg * 16 + ((lane >> 4) << 2);
        floatx4 o = accv[pg];
        o[0] += bias; o[1] += bias; o[2] += bias; o[3] += bias;
        *reinterpret_cast<floatx4*>(&out[(((size_t)b * OCN + oc) * HH + row) * WW + pcol]) = o;
    }
}

extern "C" void kernel_launch(void* const* d_in, const int* in_sizes, int n_in,
                              void* d_out, int out_size, void* d_ws, size_t ws_size,
                              hipStream_t stream) {
    const float* x      = (const float*)d_in[0];
    const float* w_off  = (const float*)d_in[1];
    const float* b_off  = (const float*)d_in[2];
    const float* w_mask = (const float*)d_in[3];
    const float* b_mask = (const float*)d_in[4];
    const float* w_dcn  = (const float*)d_in[5];
    const float* b_dcn  = (const float*)d_in[6];

    float* out     = (float*)d_out;                       // B*OC*H*W
    float* off_out = out + (size_t)BB * OCN * HW;         // B*18*H*W (output 1)

    float* mask_ws = (float*)d_ws;                        // B*9*H*W f32
    float* rebias  = mask_ws + (size_t)BB * 9 * HW;       // 32 f32 (padded)
    __hip_bfloat16* xt  = (__hip_bfloat16*)(rebias + 32); // B*HW*C bf16
    __hip_bfloat16* wTf = xt + (size_t)BB * HW * CC;      // 18*4*64*8 bf16
    __hip_bfloat16* wOf = wTf + 18 * 4 * 64 * 8;          // 18*2*64*8 bf16

    int prep_total  = 18 * 4 * 64 * 8 + 18 * 2 * 64 * 8 + 27;
    int prep_blocks = (prep_total + 255) / 256;           // 217
    transpose_prep<<<BB * 512 + prep_blocks, 256, 0, stream>>>(
        x, w_dcn, w_off, b_off, w_mask, b_mask, xt, wTf, wOf, rebias);

    offmask<<<BB * HH * 4, 256, 0, stream>>>(xt, wOf, rebias, off_out, mask_ws);

    deform<<<BB * HH * 4, 256, 0, stream>>>(xt, off_out, mask_ws, wTf, b_dcn, out);
}

// Round 8
// 41.607 us; speedup vs baseline: 18.9146x; 1.0729x over previous
//
#include <hip/hip_runtime.h>
#include <hip/hip_bf16.h>
#include <math.h>

#define BB 4
#define CC 64
#define OCN 64
#define HH 128
#define WW 128
#define HW (HH*WW)
#define KKN 9
#define CK 576            // C*KK, GEMM K
#define APAD 200          // LDS row stride (bf16) for accs tiles

typedef short short8 __attribute__((ext_vector_type(8)));
typedef float floatx4 __attribute__((ext_vector_type(4)));
typedef unsigned int uintx4 __attribute__((ext_vector_type(4)));

__device__ __forceinline__ float bf2f(__hip_bfloat16 h) {
    unsigned short u = *reinterpret_cast<unsigned short*>(&h);
    return __uint_as_float(((unsigned)u) << 16);
}
__device__ __forceinline__ short f2bfs(float f) {
    __hip_bfloat16 h = __float2bfloat16(f);
    return *reinterpret_cast<short*>(&h);
}
__device__ __forceinline__ uintx4 as_u4(short8 v) {
    union { short8 s; uintx4 u; } x; x.s = v; return x.u;
}
__device__ __forceinline__ float blo(unsigned d) { return __uint_as_float(d << 16); }
__device__ __forceinline__ float bhi(unsigned d) { return __uint_as_float(d & 0xffff0000u); }

// ---------------- transpose_prep: xt transpose + weight fragment packing, fused -------
// blocks [0, BB*512): transpose 32 pixels each. blocks [BB*512, +217): prep.
// B-frag pack: frag[((s*NT+nt)*64+l)*8+j] = W[oc = nt*16+(l&15)][kk = s*32+((l>>4)<<3)+j]
// K-order: kk = ktap*64 + c (tap-major, matches gather LDS layout).
__global__ __launch_bounds__(256) void transpose_prep(
    const float* __restrict__ x,
    const float* __restrict__ w_dcn, const float* __restrict__ w_off,
    const float* __restrict__ b_off, const float* __restrict__ w_mask,
    const float* __restrict__ b_mask,
    __hip_bfloat16* __restrict__ xt, __hip_bfloat16* __restrict__ wTf,
    __hip_bfloat16* __restrict__ wOf, float* __restrict__ rebias)
{
    int blk = blockIdx.x;
    int tid = threadIdx.x;
    if (blk < BB * 512) {
        __shared__ float tile[64][33];    // 8448 B
        int pixbase = (blk & 511) * 32;
        int b       = blk >> 9;
        const float* xb = x + (size_t)b * CC * HW;
        int p = tid & 31;
        #pragma unroll
        for (int i = 0; i < 8; ++i) {
            int c = (tid >> 5) * 8 + i;
            tile[c][p] = xb[(size_t)c * HW + pixbase + p];
        }
        __syncthreads();
        __hip_bfloat16* xo = xt + ((size_t)b * HW + pixbase) * CC;
        int pixl = tid >> 3;       // 0..31
        int c8t  = tid & 7;        // 0..7
        short8 o;
        #pragma unroll
        for (int i = 0; i < 8; ++i) o[i] = f2bfs(tile[c8t * 8 + i][pixl]);
        *reinterpret_cast<short8*>(&xo[(size_t)pixl * CC + c8t * 8]) = o;
        return;
    }
    int i = (blk - BB * 512) * 256 + tid;
    if (i < 18 * 4 * 64 * 8) {                 // wTf: 18 K-steps x 4 oc-tiles
        int jj = i & 7;
        int l  = (i >> 3) & 63;
        int nt = (i >> 9) & 3;
        int s  = i >> 11;
        int oc = nt * 16 + (l & 15);
        int kk = s * 32 + ((l >> 4) << 3) + jj;
        int c  = kk & 63;
        int kt = kk >> 6;
        wTf[i] = __float2bfloat16(w_dcn[(oc * CC + c) * 9 + kt]);
    }
    int j = i - 18 * 4 * 64 * 8;
    if (j >= 0 && j < 18 * 2 * 64 * 8) {       // wOf: 18 K-steps x 2 oc-tiles (27 used)
        int jj = j & 7;
        int l  = (j >> 3) & 63;
        int nt = (j >> 9) & 1;
        int s  = j >> 10;
        int oc = nt * 16 + (l & 15);
        int kk = s * 32 + ((l >> 4) << 3) + jj;
        int c  = kk & 63;
        int kt = kk >> 6;
        float v = 0.0f;
        if (oc < 18)      v = w_off[(oc * CC + c) * 9 + kt];
        else if (oc < 27) v = w_mask[((oc - 18) * CC + c) * 9 + kt];
        wOf[j] = __float2bfloat16(v);
    }
    int r = j - 18 * 2 * 64 * 8;
    if (r >= 0 && r < 27) rebias[r] = (r < 18) ? b_off[r] : b_mask[r - 18];
}

// ---------------- deform_fused: offset/mask conv GEMM + bilinear gather + MFMA GEMM ----
// 32 pixels/block, grid 2048, 4 waves.
// Phase A (offmask): 3x3 conv as [32x576]x[576x32] GEMM; offsets -> global + LDS,
//                    sigmoid(mask) -> LDS.   wave = (nt = wv&1 oc-tile, pg = wv>>1).
// Phase B: tap setup from LDS offsets.
// Phase C (deform): rolling gather batches + MFMA; wave = oc-tile wv.
__global__ __launch_bounds__(256, 8) void deform_fused(
    const __hip_bfloat16* __restrict__ xt,
    const __hip_bfloat16* __restrict__ wTf, const __hip_bfloat16* __restrict__ wOf,
    const float* __restrict__ rebias, const float* __restrict__ b_dcn,
    float* __restrict__ off_out, float* __restrict__ out)
{
    __shared__ __align__(16) __hip_bfloat16 accs[32][APAD];   // 12800 B
    __shared__ uintx4 tabs[KKN][32];                          // 4608 B
    __shared__ float offs_l[18][33];                          // 2376 B
    __shared__ float ms_l[KKN][33];                           // 1188 B

    int tid  = threadIdx.x;
    int lane = tid & 63;
    int wv   = __builtin_amdgcn_readfirstlane(tid >> 6);
    int pix  = tid >> 3;          // 0..31 (gather)
    int c8   = tid & 7;           // 0..7  (gather)
    int spix = (tid >> 3) & 31;   // staging pixel
    int nt   = wv & 1;            // offmask oc-tile
    int pg   = wv >> 1;           // offmask pixel-group

    int wo0 = (blockIdx.x & 3) * 32;
    int row = (blockIdx.x >> 2) & (HH - 1);
    int b   = blockIdx.x >> 9;

    const __hip_bfloat16* xtb16 = xt + (size_t)b * HW * CC;
    const short8 zero8 = {0,0,0,0,0,0,0,0};
    int kreg = (lane >> 4) << 3;

    // ================= Phase A: offset/mask 3x3 conv =================
    floatx4 accom = {0, 0, 0, 0};
    for (int chunk = 0; chunk < 3; ++chunk) {   // chunk = ky row of the 3x3
        int y = row + chunk - 1;
        bool yvalid = (unsigned)y < (unsigned)HH;
        short8 v[3];
        #pragma unroll
        for (int kl = 0; kl < 3; ++kl) {
            int xw = wo0 + spix + kl - 1;
            bool valid = yvalid && ((unsigned)xw < (unsigned)WW);
            v[kl] = zero8;
            if (valid)
                v[kl] = *reinterpret_cast<const short8*>(xtb16 + ((size_t)y * WW + xw) * CC + c8 * 8);
        }
        #pragma unroll
        for (int kl = 0; kl < 3; ++kl)
            *reinterpret_cast<short8*>(&accs[spix][kl * 64 + c8 * 8]) = v[kl];
        __syncthreads();

        #pragma unroll
        for (int step = 0; step < 6; ++step) {
            int s = chunk * 6 + step;
            short8 bfrag = *(reinterpret_cast<const short8*>(wOf) + (size_t)(s * 2 + nt) * 64 + lane);
            short8 a = *reinterpret_cast<const short8*>(&accs[pg * 16 + (lane & 15)][step * 32 + kreg]);
            accom = __builtin_amdgcn_mfma_f32_16x16x32_bf16(a, bfrag, accom, 0, 0, 0);
        }
        __syncthreads();
    }

    // epilogue A: offsets -> global (output 1) + LDS; mask -> sigmoid -> LDS
    {
        int oc = nt * 16 + (lane & 15);
        int pcol = pg * 16 + ((lane >> 4) << 2);     // pixel 0..28 within tile
        if (oc < 18) {
            float bias = rebias[oc];
            floatx4 o = accom;
            o[0] += bias; o[1] += bias; o[2] += bias; o[3] += bias;
            *reinterpret_cast<floatx4*>(&off_out[(((size_t)b * 18 + oc) * HH + row) * WW + wo0 + pcol]) = o;
            offs_l[oc][pcol]     = o[0];
            offs_l[oc][pcol + 1] = o[1];
            offs_l[oc][pcol + 2] = o[2];
            offs_l[oc][pcol + 3] = o[3];
        } else if (oc < 27) {
            float bias = rebias[oc];
            #pragma unroll
            for (int q = 0; q < 4; ++q)
                ms_l[oc - 18][pcol + q] = 1.0f / (1.0f + expf(-(accom[q] + bias)));
        }
    }
    __syncthreads();

    // ================= Phase B: bilinear tap setup from LDS =================
    for (int e = tid; e < KKN * 32; e += 256) {
        int k = e >> 5, p = e & 31;
        float dy = offs_l[2 * k][p];
        float dx = offs_l[2 * k + 1][p];
        float m  = ms_l[k][p];
        float py = dy + (float)(k / 3) + (float)(row - 1);
        float px = dx + (float)(k % 3) + (float)(wo0 + p - 1);
        float y0f = floorf(py), x0f = floorf(px);
        float ly = py - y0f, lx = px - x0f;
        int y0 = (int)y0f, x0 = (int)x0f;
        uintx4 rec;
        #pragma unroll
        for (int t = 0; t < 4; ++t) {
            int yi = y0 + (t >> 1), xi = x0 + (t & 1);
            float wy = (t >> 1) ? ly : 1.0f - ly;
            float wx = (t & 1)  ? lx : 1.0f - lx;
            bool valid = ((unsigned)yi < (unsigned)HH) && ((unsigned)xi < (unsigned)WW);
            int yc = min(max(yi, 0), HH - 1);
            int xc = min(max(xi, 0), WW - 1);
            __hip_bfloat16 hw = __float2bfloat16(valid ? wy * wx * m : 0.0f);
            unsigned short wb = *reinterpret_cast<unsigned short*>(&hw);
            rec[t] = (unsigned)(yc * WW + xc) | ((unsigned)wb << 16);
        }
        tabs[k][p] = rec;
    }
    __syncthreads();

    // ================= Phase C: deform gather + GEMM =================
    const char* xtb = (const char*)xtb16;
    int co = c8 * 16;             // byte offset of this thread's 8 channels

    short8 buf[2][4];
    uintx4 tb[2];
    floatx4 accv[2] = {{0,0,0,0},{0,0,0,0}};

#define ISSUE(G9) do { \
    uintx4 _t = tabs[(G9)][pix]; \
    tb[(G9) & 1] = _t; \
    buf[(G9) & 1][0] = *(const short8*)(xtb + ((_t[0] & 0xffffu) << 7) + co); \
    buf[(G9) & 1][1] = *(const short8*)(xtb + ((_t[1] & 0xffffu) << 7) + co); \
    buf[(G9) & 1][2] = *(const short8*)(xtb + ((_t[2] & 0xffffu) << 7) + co); \
    buf[(G9) & 1][3] = *(const short8*)(xtb + ((_t[3] & 0xffffu) << 7) + co); \
} while (0)

#define COMBINE(G9) do { \
    float aA[8] = {0,0,0,0,0,0,0,0}; \
    _Pragma("unroll") \
    for (int t = 0; t < 4; ++t) { \
        float wt = __uint_as_float(tb[(G9) & 1][t] & 0xffff0000u); \
        uintx4 dA = as_u4(buf[(G9) & 1][t]); \
        _Pragma("unroll") \
        for (int jq = 0; jq < 4; ++jq) { \
            aA[2 * jq]     = fmaf(wt, blo(dA[jq]), aA[2 * jq]); \
            aA[2 * jq + 1] = fmaf(wt, bhi(dA[jq]), aA[2 * jq + 1]); \
        } \
    } \
    short8 oA; \
    _Pragma("unroll") \
    for (int jq = 0; jq < 8; ++jq) { oA[jq] = f2bfs(aA[jq]); } \
    *reinterpret_cast<short8*>(&accs[pix][((G9) % 3) * 64 + c8 * 8]) = oA; \
} while (0)

#define MFMA_CHUNK(CH) do { \
    _Pragma("unroll") \
    for (int step = 0; step < 6; ++step) { \
        int s = (CH) * 6 + step; \
        short8 bfrag = *(reinterpret_cast<const short8*>(wTf) + (size_t)(s * 4 + wv) * 64 + lane); \
        _Pragma("unroll") \
        for (int pgq = 0; pgq < 2; ++pgq) { \
            short8 a = *reinterpret_cast<const short8*>(&accs[pgq * 16 + (lane & 15)][step * 32 + kreg]); \
            accv[pgq] = __builtin_amdgcn_mfma_f32_16x16x32_bf16(a, bfrag, accv[pgq], 0, 0, 0); \
        } \
    } \
} while (0)

    ISSUE(0);
    // ---- chunk 0 ----
    ISSUE(1); COMBINE(0);
    ISSUE(2); COMBINE(1); COMBINE(2);
    __syncthreads();
    ISSUE(3);                       // prefetch chunk1 batch0, flies across MFMA+barrier
    MFMA_CHUNK(0);
    asm volatile("s_waitcnt lgkmcnt(0)" ::: "memory");
    __builtin_amdgcn_s_barrier();   // raw: does NOT drain vmcnt (keep prefetch in flight)
    // ---- chunk 1 ----
    ISSUE(4); COMBINE(3);
    ISSUE(5); COMBINE(4); COMBINE(5);
    __syncthreads();
    ISSUE(6);
    MFMA_CHUNK(1);
    asm volatile("s_waitcnt lgkmcnt(0)" ::: "memory");
    __builtin_amdgcn_s_barrier();
    // ---- chunk 2 ----
    ISSUE(7); COMBINE(6);
    ISSUE(8); COMBINE(7); COMBINE(8);
    __syncthreads();
    MFMA_CHUNK(2);

#undef ISSUE
#undef COMBINE
#undef MFMA_CHUNK

    // epilogue C: wave wv owns oc-tile wv. D: col=lane&15 (oc), row=(lane>>4)*4+reg (pixel)
    int oc = wv * 16 + (lane & 15);
    float bias = b_dcn[oc];
    #pragma unroll
    for (int pgq = 0; pgq < 2; ++pgq) {
        int pcol = wo0 + pgq * 16 + ((lane >> 4) << 2);
        floatx4 o = accv[pgq];
        o[0] += bias; o[1] += bias; o[2] += bias; o[3] += bias;
        *reinterpret_cast<floatx4*>(&out[(((size_t)b * OCN + oc) * HH + row) * WW + pcol]) = o;
    }
}

extern "C" void kernel_launch(void* const* d_in, const int* in_sizes, int n_in,
                              void* d_out, int out_size, void* d_ws, size_t ws_size,
                              hipStream_t stream) {
    const float* x      = (const float*)d_in[0];
    const float* w_off  = (const float*)d_in[1];
    const float* b_off  = (const float*)d_in[2];
    const float* w_mask = (const float*)d_in[3];
    const float* b_mask = (const float*)d_in[4];
    const float* w_dcn  = (const float*)d_in[5];
    const float* b_dcn  = (const float*)d_in[6];

    float* out     = (float*)d_out;                       // B*OC*H*W
    float* off_out = out + (size_t)BB * OCN * HW;         // B*18*H*W (output 1)

    float* rebias  = (float*)d_ws;                        // 32 f32
    __hip_bfloat16* xt  = (__hip_bfloat16*)(rebias + 32); // B*HW*C bf16
    __hip_bfloat16* wTf = xt + (size_t)BB * HW * CC;      // 18*4*64*8 bf16
    __hip_bfloat16* wOf = wTf + 18 * 4 * 64 * 8;          // 18*2*64*8 bf16

    int prep_total  = 18 * 4 * 64 * 8 + 18 * 2 * 64 * 8 + 27;
    int prep_blocks = (prep_total + 255) / 256;           // 217
    transpose_prep<<<BB * 512 + prep_blocks, 256, 0, stream>>>(
        x, w_dcn, w_off, b_off, w_mask, b_mask, xt, wTf, wOf, rebias);

    deform_fused<<<BB * HH * 4, 256, 0, stream>>>(
        xt, wTf, wOf, rebias, b_dcn, off_out, out);
}